// Round 1
// baseline (1865.844 us; speedup 1.0000x reference)
//
#include <hip/hip_runtime.h>

// Problem constants (from reference setup_inputs)
#define T_ 4
#define B_ 16
#define C_ 512
#define N_ 1024
#define H_ 8
#define D_ 64
#define SPK_ELEMS (33554432ull)   // T*B*C*N

// workspace layout (bytes)
#define SQ_OFF  (0ull)
#define SK_OFF  (33554432ull)
#define SV_OFF  (67108864ull)
#define SA_OFF  (100663296ull)
#define KV_OFF  (134217728ull)                 // fp32, T*B*H*D*D = 2,097,152 elems
#define WT_OFF  (142606336ull)                 // 4 transposed 512x512 fp32 weights
// total: 146,800,640 bytes

#define FMA16(A, av, bv) \
  A[0][0] = fmaf(av.x, bv.x, A[0][0]); A[0][1] = fmaf(av.x, bv.y, A[0][1]); \
  A[0][2] = fmaf(av.x, bv.z, A[0][2]); A[0][3] = fmaf(av.x, bv.w, A[0][3]); \
  A[1][0] = fmaf(av.y, bv.x, A[1][0]); A[1][1] = fmaf(av.y, bv.y, A[1][1]); \
  A[1][2] = fmaf(av.y, bv.z, A[1][2]); A[1][3] = fmaf(av.y, bv.w, A[1][3]); \
  A[2][0] = fmaf(av.z, bv.x, A[2][0]); A[2][1] = fmaf(av.z, bv.y, A[2][1]); \
  A[2][2] = fmaf(av.z, bv.z, A[2][2]); A[2][3] = fmaf(av.z, bv.w, A[2][3]); \
  A[3][0] = fmaf(av.w, bv.x, A[3][0]); A[3][1] = fmaf(av.w, bv.y, A[3][1]); \
  A[3][2] = fmaf(av.w, bv.z, A[3][2]); A[3][3] = fmaf(av.w, bv.w, A[3][3]);

// ---------------------------------------------------------------------------
// Kernel 0: transpose the four 512x512 weight matrices: WT[c][o] = W[o][c]
// so GEMM staging loads are coalesced along the output-channel axis.
// ---------------------------------------------------------------------------
__global__ __launch_bounds__(256) void transpose_w(
    const float* __restrict__ w0, const float* __restrict__ w1,
    const float* __restrict__ w2, const float* __restrict__ w3,
    float* __restrict__ wt_all)
{
  __shared__ float tile[32][33];
  const float* src = (blockIdx.z == 0) ? w0 : (blockIdx.z == 1) ? w1
                   : (blockIdx.z == 2) ? w2 : w3;
  float* dst = wt_all + (size_t)blockIdx.z * C_ * C_;
  const int tx = threadIdx.x, ty = threadIdx.y;
  const int o0 = blockIdx.y * 32, c0 = blockIdx.x * 32;
#pragma unroll
  for (int k = 0; k < 4; ++k)
    tile[ty + k * 8][tx] = src[(size_t)(o0 + ty + k * 8) * C_ + c0 + tx];
  __syncthreads();
#pragma unroll
  for (int k = 0; k < 4; ++k)
    dst[(size_t)(c0 + ty + k * 8) * C_ + o0 + tx] = tile[tx][ty + k * 8];
}

// ---------------------------------------------------------------------------
// Kernel 1: fused q/k/v 1x1-conv GEMM + multi-step LIF.
// Block = 64 o-rows x 64 n-cols, all T=4 timesteps accumulated in registers,
// LIF applied across t in the epilogue. Spikes written as uint8.
// grid: (N/64, (C/64)*B, 3 projections), block 256.
// ---------------------------------------------------------------------------
__global__ __launch_bounds__(256) void qkv_lif(
    const float* __restrict__ x, const float* __restrict__ wt_all,
    const float* __restrict__ bq, const float* __restrict__ bk,
    const float* __restrict__ bv, unsigned char* __restrict__ spikes_base)
{
  __shared__ float Ws[32][64];        // [k][o]
  __shared__ float Xs[T_][32][64];    // [t][k][n]
  const int tid = threadIdx.x;
  const int tx = tid & 15, ty = tid >> 4;
  const int tx4 = tx * 4, ty4 = ty * 4;
  const int n0 = blockIdx.x * 64;
  const int o0 = (blockIdx.y & 7) * 64;
  const int b  = blockIdx.y >> 3;
  const int p  = blockIdx.z;

  const float* wt = wt_all + (size_t)p * C_ * C_;
  const float* bias = (p == 0) ? bq : (p == 1) ? bk : bv;
  unsigned char* sp = spikes_base + (size_t)p * SPK_ELEMS;

  float acc[T_][4][4];
#pragma unroll
  for (int t = 0; t < T_; ++t)
#pragma unroll
    for (int i = 0; i < 4; ++i)
#pragma unroll
      for (int j = 0; j < 4; ++j) acc[t][i][j] = 0.f;

  for (int kc = 0; kc < C_; kc += 32) {
    __syncthreads();
#pragma unroll
    for (int l = 0; l < 2; ++l) {
      int idx = tid + 256 * l;
      int r = idx >> 4, c4 = (idx & 15) * 4;
      *(float4*)&Ws[r][c4] = *(const float4*)&wt[(size_t)(kc + r) * C_ + o0 + c4];
    }
#pragma unroll
    for (int t = 0; t < T_; ++t) {
      const float* xb = x + ((size_t)(t * B_ + b) * C_ + kc) * N_ + n0;
#pragma unroll
      for (int l = 0; l < 2; ++l) {
        int idx = tid + 256 * l;
        int r = idx >> 4, c4 = (idx & 15) * 4;
        *(float4*)&Xs[t][r][c4] = *(const float4*)&xb[(size_t)r * N_ + c4];
      }
    }
    __syncthreads();
#pragma unroll 4
    for (int kk = 0; kk < 32; ++kk) {
      float4 wv = *(float4*)&Ws[kk][ty4];
#pragma unroll
      for (int t = 0; t < T_; ++t) {
        float4 xv = *(float4*)&Xs[t][kk][tx4];
        FMA16(acc[t], wv, xv)
      }
    }
  }

  // epilogue: bias + LIF over t (v=0 init; v += (y-v)/2; spike v>=1; hard reset)
  float4 b4 = *(const float4*)&bias[o0 + ty4];
  float barr[4] = {b4.x, b4.y, b4.z, b4.w};
  float vm[4][4];
#pragma unroll
  for (int i = 0; i < 4; ++i)
#pragma unroll
    for (int j = 0; j < 4; ++j) vm[i][j] = 0.f;

#pragma unroll
  for (int t = 0; t < T_; ++t) {
#pragma unroll
    for (int i = 0; i < 4; ++i) {
      unsigned char sj[4];
#pragma unroll
      for (int j = 0; j < 4; ++j) {
        float y = acc[t][i][j] + barr[i];
        float v = vm[i][j];
        v = v + (y - v) * 0.5f;
        bool s = (v >= 1.0f);
        sj[j] = s ? 1 : 0;
        vm[i][j] = s ? 0.f : v;
      }
      *(uchar4*)&sp[((size_t)(t * B_ + b) * C_ + o0 + ty4 + i) * N_ + n0 + tx4] =
          make_uchar4(sj[0], sj[1], sj[2], sj[3]);
    }
  }
}

// ---------------------------------------------------------------------------
// Kernel 2: kv[t,b,h,d,e] = sum_n k_s[t,b,64h+d,n] * v_s[t,b,64h+e,n]
// Binary inputs -> exact integer fp32 result. grid (H, B, T), block 256.
// ---------------------------------------------------------------------------
__global__ __launch_bounds__(256) void kv_kernel(
    const unsigned char* __restrict__ sk, const unsigned char* __restrict__ sv,
    float* __restrict__ kvout)
{
  __shared__ float Ksh[64][68];   // [n][d] transposed; stride 68 keeps 16B align
  __shared__ float Vsh[64][68];
  const int tid = threadIdx.x;
  const int tx = tid & 15, ty = tid >> 4;
  const int tx4 = tx * 4, ty4 = ty * 4;
  const int h = blockIdx.x, b = blockIdx.y, t = blockIdx.z;

  const unsigned char* kb = sk + ((size_t)(t * B_ + b) * C_ + h * D_) * N_;
  const unsigned char* vb = sv + ((size_t)(t * B_ + b) * C_ + h * D_) * N_;

  float acc[4][4];
#pragma unroll
  for (int i = 0; i < 4; ++i)
#pragma unroll
    for (int j = 0; j < 4; ++j) acc[i][j] = 0.f;

  for (int nc = 0; nc < N_; nc += 64) {
    __syncthreads();
#pragma unroll
    for (int l = 0; l < 4; ++l) {
      int idx = tid + 256 * l;
      int dd = idx >> 4, n4 = (idx & 15) * 4;
      uchar4 ku = *(const uchar4*)&kb[(size_t)dd * N_ + nc + n4];
      uchar4 vu = *(const uchar4*)&vb[(size_t)dd * N_ + nc + n4];
      Ksh[n4 + 0][dd] = (float)ku.x; Ksh[n4 + 1][dd] = (float)ku.y;
      Ksh[n4 + 2][dd] = (float)ku.z; Ksh[n4 + 3][dd] = (float)ku.w;
      Vsh[n4 + 0][dd] = (float)vu.x; Vsh[n4 + 1][dd] = (float)vu.y;
      Vsh[n4 + 2][dd] = (float)vu.z; Vsh[n4 + 3][dd] = (float)vu.w;
    }
    __syncthreads();
#pragma unroll 8
    for (int nn = 0; nn < 64; ++nn) {
      float4 kvec = *(float4*)&Ksh[nn][ty4];
      float4 vvec = *(float4*)&Vsh[nn][tx4];
      FMA16(acc, kvec, vvec)
    }
  }

  float* o = kvout + ((size_t)(t * B_ + b) * H_ + h) * (D_ * D_);
#pragma unroll
  for (int i = 0; i < 4; ++i)
    *(float4*)&o[(ty4 + i) * D_ + tx4] =
        make_float4(acc[i][0], acc[i][1], acc[i][2], acc[i][3]);
}

// ---------------------------------------------------------------------------
// Kernel 3: out[t,b,h,n,e] = 0.125 * sum_d q[n,d]*kv[d,e]; then LIF across t.
// Exact integer arithmetic -> bit-exact spikes. grid (N/64, H, B), block 256.
// ---------------------------------------------------------------------------
__global__ __launch_bounds__(256) void attn_lif(
    const unsigned char* __restrict__ sq, const float* __restrict__ kv,
    unsigned char* __restrict__ sa)
{
  __shared__ float KVs[64][64];   // [d][e]
  __shared__ float Qs[64][64];    // [d][n]
  const int tid = threadIdx.x;
  const int tx = tid & 15, ty = tid >> 4;
  const int tx4 = tx * 4, ty4 = ty * 4;
  const int n0 = blockIdx.x * 64;
  const int h = blockIdx.y, b = blockIdx.z;

  float vm[4][4];
#pragma unroll
  for (int i = 0; i < 4; ++i)
#pragma unroll
    for (int j = 0; j < 4; ++j) vm[i][j] = 0.f;

  for (int t = 0; t < T_; ++t) {
    __syncthreads();
    const float* kvb = kv + ((size_t)(t * B_ + b) * H_ + h) * (D_ * D_);
    const unsigned char* qb = sq + ((size_t)(t * B_ + b) * C_ + h * D_) * N_ + n0;
#pragma unroll
    for (int l = 0; l < 4; ++l) {
      int idx = tid + 256 * l;
      int r = idx >> 4, c4 = (idx & 15) * 4;
      *(float4*)&KVs[r][c4] = *(const float4*)&kvb[r * D_ + c4];
      uchar4 qu = *(const uchar4*)&qb[(size_t)r * N_ + c4];
      *(float4*)&Qs[r][c4] =
          make_float4((float)qu.x, (float)qu.y, (float)qu.z, (float)qu.w);
    }
    __syncthreads();

    float acc[4][4];
#pragma unroll
    for (int i = 0; i < 4; ++i)
#pragma unroll
      for (int j = 0; j < 4; ++j) acc[i][j] = 0.f;

#pragma unroll 8
    for (int dd = 0; dd < 64; ++dd) {
      float4 qv  = *(float4*)&Qs[dd][ty4];   // q[n0+ty4+i][dd]
      float4 kvv = *(float4*)&KVs[dd][tx4];  // kv[dd][tx4+j]
      FMA16(acc, qv, kvv)
    }

    // LIF; spikes to channel c = 64h + e, spatial n
#pragma unroll
    for (int j = 0; j < 4; ++j) {
      unsigned char si[4];
#pragma unroll
      for (int i = 0; i < 4; ++i) {
        float y = acc[i][j] * 0.125f;
        float v = vm[i][j];
        v = v + (y - v) * 0.5f;
        bool s = (v >= 1.0f);
        si[i] = s ? 1 : 0;
        vm[i][j] = s ? 0.f : v;
      }
      *(uchar4*)&sa[((size_t)(t * B_ + b) * C_ + h * D_ + tx4 + j) * N_ + n0 + ty4] =
          make_uchar4(si[0], si[1], si[2], si[3]);
    }
  }
}

// ---------------------------------------------------------------------------
// Kernel 4: proj 1x1-conv GEMM + connecting LIF (with identity shortcut x).
// Same structure as kernel 1; writes final fp32 spikes to d_out.
// grid: (N/64, (C/64)*B), block 256.
// ---------------------------------------------------------------------------
__global__ __launch_bounds__(256) void proj_conn(
    const float* __restrict__ x, const float* __restrict__ wt_all,
    const float* __restrict__ bp, const unsigned char* __restrict__ sa,
    float* __restrict__ out)
{
  __shared__ float Ws[32][64];        // [k][o]
  __shared__ float Ss[T_][32][64];    // [t][k][n]
  const int tid = threadIdx.x;
  const int tx = tid & 15, ty = tid >> 4;
  const int tx4 = tx * 4, ty4 = ty * 4;
  const int n0 = blockIdx.x * 64;
  const int o0 = (blockIdx.y & 7) * 64;
  const int b  = blockIdx.y >> 3;

  const float* wt = wt_all + 3ull * C_ * C_;   // WpT

  float acc[T_][4][4];
#pragma unroll
  for (int t = 0; t < T_; ++t)
#pragma unroll
    for (int i = 0; i < 4; ++i)
#pragma unroll
      for (int j = 0; j < 4; ++j) acc[t][i][j] = 0.f;

  for (int kc = 0; kc < C_; kc += 32) {
    __syncthreads();
#pragma unroll
    for (int l = 0; l < 2; ++l) {
      int idx = tid + 256 * l;
      int r = idx >> 4, c4 = (idx & 15) * 4;
      *(float4*)&Ws[r][c4] = *(const float4*)&wt[(size_t)(kc + r) * C_ + o0 + c4];
    }
#pragma unroll
    for (int t = 0; t < T_; ++t) {
      const unsigned char* sb = sa + ((size_t)(t * B_ + b) * C_ + kc) * N_ + n0;
#pragma unroll
      for (int l = 0; l < 2; ++l) {
        int idx = tid + 256 * l;
        int r = idx >> 4, c4 = (idx & 15) * 4;
        uchar4 su = *(const uchar4*)&sb[(size_t)r * N_ + c4];
        *(float4*)&Ss[t][r][c4] =
            make_float4((float)su.x, (float)su.y, (float)su.z, (float)su.w);
      }
    }
    __syncthreads();
#pragma unroll 4
    for (int kk = 0; kk < 32; ++kk) {
      float4 wv = *(float4*)&Ws[kk][ty4];
#pragma unroll
      for (int t = 0; t < T_; ++t) {
        float4 sv = *(float4*)&Ss[t][kk][tx4];
        FMA16(acc[t], wv, sv)
      }
    }
  }

  // epilogue: conn_lif  v += ((P + x) - v)/2 ; spike ; hard reset ; out = spike
  float4 b4 = *(const float4*)&bp[o0 + ty4];
  float barr[4] = {b4.x, b4.y, b4.z, b4.w};
  float vm[4][4];
#pragma unroll
  for (int i = 0; i < 4; ++i)
#pragma unroll
    for (int j = 0; j < 4; ++j) vm[i][j] = 0.f;

#pragma unroll
  for (int t = 0; t < T_; ++t) {
#pragma unroll
    for (int i = 0; i < 4; ++i) {
      size_t base = ((size_t)(t * B_ + b) * C_ + o0 + ty4 + i) * N_ + n0 + tx4;
      float4 xv = *(const float4*)&x[base];
      float xarr[4] = {xv.x, xv.y, xv.z, xv.w};
      float oarr[4];
#pragma unroll
      for (int j = 0; j < 4; ++j) {
        float pv = acc[t][i][j] + barr[i];
        float v = vm[i][j];
        v = v + ((pv + xarr[j]) - v) * 0.5f;   // matches ref op order
        bool s = (v >= 1.0f);
        oarr[j] = s ? 1.0f : 0.0f;
        vm[i][j] = s ? 0.f : v;
      }
      *(float4*)&out[base] = make_float4(oarr[0], oarr[1], oarr[2], oarr[3]);
    }
  }
}

// ---------------------------------------------------------------------------
extern "C" void kernel_launch(void* const* d_in, const int* in_sizes, int n_in,
                              void* d_out, int out_size, void* d_ws, size_t ws_size,
                              hipStream_t stream)
{
  const float* x  = (const float*)d_in[0];
  const float* Wq = (const float*)d_in[1];
  const float* bq = (const float*)d_in[2];
  const float* Wk = (const float*)d_in[3];
  const float* bk = (const float*)d_in[4];
  const float* Wv = (const float*)d_in[5];
  const float* bv = (const float*)d_in[6];
  const float* Wp = (const float*)d_in[7];
  const float* bp = (const float*)d_in[8];
  (void)in_sizes; (void)n_in; (void)out_size; (void)ws_size;

  unsigned char* ws = (unsigned char*)d_ws;
  unsigned char* sq = ws + SQ_OFF;
  unsigned char* sk = ws + SK_OFF;
  unsigned char* sv = ws + SV_OFF;
  unsigned char* sa = ws + SA_OFF;
  float* kvbuf = (float*)(ws + KV_OFF);
  float* wt    = (float*)(ws + WT_OFF);
  float* out   = (float*)d_out;

  transpose_w<<<dim3(16, 16, 4), dim3(32, 8), 0, stream>>>(Wq, Wk, Wv, Wp, wt);
  qkv_lif<<<dim3(16, 128, 3), 256, 0, stream>>>(x, wt, bq, bk, bv, ws);
  kv_kernel<<<dim3(8, 16, 4), 256, 0, stream>>>(sk, sv, kvbuf);
  attn_lif<<<dim3(16, 8, 16), 256, 0, stream>>>(sq, kvbuf, sa);
  proj_conn<<<dim3(16, 128), 256, 0, stream>>>(x, wt, bp, sa, out);
}

// Round 2
// 1488.876 us; speedup vs baseline: 1.2532x; 1.2532x over previous
//
#include <hip/hip_runtime.h>

// Problem constants
#define T_ 4
#define B_ 16
#define C_ 512
#define N_ 1024
#define H_ 8
#define D_ 64
#define SPK_ELEMS (33554432ull)   // T*B*C*N

typedef short short8 __attribute__((ext_vector_type(8)));
typedef float f32x4 __attribute__((ext_vector_type(4)));

// ---------------- new-path workspace layout (bytes) ----------------
// sq:  [0, 33554432)            uint8 spikes q  [t,b,c,n]
// sk:  [33554432, 67108864)     uint8 spikes k
// sv:  [67108864, 100663296)    uint8 spikes v
// kv:  [100663296, 109051904)   fp32  [t,b,h,d,e]
// wb:  [109051904, 115343360)   bf16  [p=4][digit=3][512][512]
// xs:  [115343360, 316669952)   bf16  [digit=3][t][b][n=1024][c=512]
// sa:  aliases xs digit-0 region (xs dead before attn_lif writes it)
#define NEW_WS_NEED 316669952ull
#define KV_OFF_N  100663296ull
#define WB_OFF_N  109051904ull
#define XS_OFF_N  115343360ull

// fallback (round-1) layout
#define SA_OFF_O  100663296ull
#define KV_OFF_O  134217728ull
#define WT_OFF_O  142606336ull

#define FMA16(A, av, bv) \
  A[0][0] = fmaf(av.x, bv.x, A[0][0]); A[0][1] = fmaf(av.x, bv.y, A[0][1]); \
  A[0][2] = fmaf(av.x, bv.z, A[0][2]); A[0][3] = fmaf(av.x, bv.w, A[0][3]); \
  A[1][0] = fmaf(av.y, bv.x, A[1][0]); A[1][1] = fmaf(av.y, bv.y, A[1][1]); \
  A[1][2] = fmaf(av.y, bv.z, A[1][2]); A[1][3] = fmaf(av.y, bv.w, A[1][3]); \
  A[2][0] = fmaf(av.z, bv.x, A[2][0]); A[2][1] = fmaf(av.z, bv.y, A[2][1]); \
  A[2][2] = fmaf(av.z, bv.z, A[2][2]); A[2][3] = fmaf(av.z, bv.w, A[2][3]); \
  A[3][0] = fmaf(av.w, bv.x, A[3][0]); A[3][1] = fmaf(av.w, bv.y, A[3][1]); \
  A[3][2] = fmaf(av.w, bv.z, A[3][2]); A[3][3] = fmaf(av.w, bv.w, A[3][3]);

__device__ __forceinline__ unsigned short bf_rne(float f) {
  unsigned u = __float_as_uint(f);
  unsigned r = (u + 0x7FFFu + ((u >> 16) & 1u)) >> 16;
  return (unsigned short)r;
}
__device__ __forceinline__ float bf2f(unsigned short h) {
  return __uint_as_float(((unsigned)h) << 16);
}

#define GLD16(gp, loff) \
  __builtin_amdgcn_global_load_lds( \
      (const __attribute__((address_space(1))) void*)(gp), \
      (__attribute__((address_space(3))) void*)(lds + (loff)), 16, 0, 0)

// ===========================================================================
// NEW PATH
// ===========================================================================

// W [4 mats][512][512] fp32 -> wb [p][3][512][512] bf16 digits
__global__ __launch_bounds__(256) void convert_w(
    const float* __restrict__ w0, const float* __restrict__ w1,
    const float* __restrict__ w2, const float* __restrict__ w3,
    unsigned short* __restrict__ wb)
{
  int idx = blockIdx.x * 256 + threadIdx.x;      // 0..1048575
  int p = idx >> 18, rem = idx & 262143;
  const float* src = (p == 0) ? w0 : (p == 1) ? w1 : (p == 2) ? w2 : w3;
  float v = src[rem];
  unsigned short h1 = bf_rne(v);
  float r1 = v - bf2f(h1);
  unsigned short h2 = bf_rne(r1);
  float r2 = r1 - bf2f(h2);
  unsigned short h3 = bf_rne(r2);
  size_t base = ((size_t)(p * 3)) << 18;
  wb[base + rem] = h1;
  wb[base + 262144 + rem] = h2;
  wb[base + 524288 + rem] = h3;
}

// x [t,b,c,n] fp32 -> xs [digit][t,b,n,c] bf16 (transposed inner dims)
__global__ __launch_bounds__(256) void convert_x(
    const float* __restrict__ x, unsigned short* __restrict__ xs)
{
  __shared__ float tile[32][33];
  const int tb = blockIdx.z;
  const int c0 = blockIdx.y * 32, n0 = blockIdx.x * 32;
  const int tx = threadIdx.x, ty = threadIdx.y;
  const float* src = x + ((size_t)tb * C_ + c0) * N_ + n0;
#pragma unroll
  for (int k = 0; k < 4; ++k)
    tile[ty + 8 * k][tx] = src[(size_t)(ty + 8 * k) * N_ + tx];
  __syncthreads();
#pragma unroll
  for (int k = 0; k < 4; ++k) {
    int r = ty + 8 * k;                       // n-offset within tile
    float v = tile[tx][r];                    // element (c=c0+tx, n=n0+r)
    unsigned short h1 = bf_rne(v);
    float r1 = v - bf2f(h1);
    unsigned short h2 = bf_rne(r1);
    float r2 = r1 - bf2f(h2);
    unsigned short h3 = bf_rne(r2);
    size_t o = ((size_t)tb * N_ + n0 + r) * C_ + c0 + tx;
    xs[o] = h1;
    xs[o + 33554432ull] = h2;
    xs[o + 67108864ull] = h3;
  }
}

// Fused q/k/v GEMM (bf16 digit MFMA) + LIF. Block tile 128o x 32n x 4t.
// grid: x = 4 o-tiles * 32 n-tiles = 128, y = b(16), z = p(3)
__global__ __launch_bounds__(256) void qkv_mfma(
    const unsigned short* __restrict__ wb, const unsigned short* __restrict__ xs,
    const float* __restrict__ bq, const float* __restrict__ bk,
    const float* __restrict__ bv, unsigned char* __restrict__ spikes_base)
{
  // LDS: WS[3][128][32] bf16 (24KB) + XS[3][4][32][32] bf16 (24KB)
  __shared__ __align__(16) char lds[49152];
  const int tid = threadIdx.x;
  const int lane = tid & 63, wave = tid >> 6;
  const int ln15 = lane & 15, lq = lane >> 4;
  const int ot = blockIdx.x & 3, ntb = blockIdx.x >> 2;
  const int o0 = ot * 128, n0 = ntb * 32;
  const int b = blockIdx.y, p = blockIdx.z;

  // staging sources: 12 x 16B per thread per k-iter (48KB total)
  const unsigned short* gsrc[12];
#pragma unroll
  for (int i = 0; i < 12; ++i) {
    int u = i * 256 + tid;
    if (u < 1536) {               // W region
      int s = u >> 9, rem = u & 511;
      int row = rem >> 2, pc = rem & 3;
      int lc = pc ^ ((row >> 1) & 3);
      gsrc[i] = wb + (((size_t)(p * 3 + s)) << 18) + (size_t)(o0 + row) * C_ + lc * 8;
    } else {                      // X region
      int v = u - 1536;
      int s = v >> 9, rem = v & 511;
      int t = rem >> 7, rem2 = rem & 127;
      int row = rem2 >> 2, pc = rem2 & 3;
      int lc = pc ^ ((row >> 1) & 3);
      gsrc[i] = xs + ((size_t)s * 33554432ull) +
                ((size_t)((t * B_ + b) * N_ + n0 + row)) * C_ + lc * 8;
    }
  }

  f32x4 acc1[T_][2][2], acc2[T_][2][2];
#pragma unroll
  for (int t = 0; t < T_; ++t)
#pragma unroll
    for (int mt = 0; mt < 2; ++mt)
#pragma unroll
      for (int nt = 0; nt < 2; ++nt) {
        acc1[t][mt][nt] = (f32x4){0.f, 0.f, 0.f, 0.f};
        acc2[t][mt][nt] = (f32x4){0.f, 0.f, 0.f, 0.f};
      }

  // loop-invariant LDS frag offsets
  int offA[3][2], offB[3][2];
#pragma unroll
  for (int s = 0; s < 3; ++s) {
#pragma unroll
    for (int mt = 0; mt < 2; ++mt) {
      int r = wave * 32 + mt * 16 + ln15;
      offA[s][mt] = s * 8192 + r * 64 + ((lq ^ ((r >> 1) & 3)) << 4);
    }
#pragma unroll
    for (int nt = 0; nt < 2; ++nt) {
      int n = nt * 16 + ln15;
      offB[s][nt] = 24576 + s * 8192 + n * 64 + ((lq ^ ((n >> 1) & 3)) << 4);
    }
  }

  for (int kk = 0; kk < 16; ++kk) {
    // async stage this k-slab (linear LDS dest = wave base + lane*16)
#pragma unroll
    for (int i = 0; i < 12; ++i)
      GLD16(gsrc[i], i * 4096 + (tid & 192) * 16);
    __syncthreads();

    short8 wa[3][2];
#pragma unroll
    for (int s = 0; s < 3; ++s)
#pragma unroll
      for (int mt = 0; mt < 2; ++mt)
        wa[s][mt] = *(const short8*)&lds[offA[s][mt]];

#pragma unroll
    for (int t = 0; t < T_; ++t) {
      short8 xb[3][2];
#pragma unroll
      for (int s = 0; s < 3; ++s)
#pragma unroll
        for (int nt = 0; nt < 2; ++nt)
          xb[s][nt] = *(const short8*)&lds[offB[s][nt] + t * 2048];
#pragma unroll
      for (int mt = 0; mt < 2; ++mt)
#pragma unroll
        for (int nt = 0; nt < 2; ++nt) {
          acc1[t][mt][nt] = __builtin_amdgcn_mfma_f32_16x16x32_bf16(
              wa[0][mt], xb[0][nt], acc1[t][mt][nt], 0, 0, 0);
          acc2[t][mt][nt] = __builtin_amdgcn_mfma_f32_16x16x32_bf16(
              wa[0][mt], xb[1][nt], acc2[t][mt][nt], 0, 0, 0);
          acc2[t][mt][nt] = __builtin_amdgcn_mfma_f32_16x16x32_bf16(
              wa[1][mt], xb[0][nt], acc2[t][mt][nt], 0, 0, 0);
          acc2[t][mt][nt] = __builtin_amdgcn_mfma_f32_16x16x32_bf16(
              wa[0][mt], xb[2][nt], acc2[t][mt][nt], 0, 0, 0);
          acc2[t][mt][nt] = __builtin_amdgcn_mfma_f32_16x16x32_bf16(
              wa[2][mt], xb[0][nt], acc2[t][mt][nt], 0, 0, 0);
          acc2[t][mt][nt] = __builtin_amdgcn_mfma_f32_16x16x32_bf16(
              wa[1][mt], xb[1][nt], acc2[t][mt][nt], 0, 0, 0);
        }
    }
    __syncthreads();
#pragma unroll
    for (int i = 0; i < 12; ++i) gsrc[i] += 32;
  }

  // epilogue: bias + LIF over t
  const float* bias = (p == 0) ? bq : (p == 1) ? bk : bv;
  unsigned char* sp = spikes_base + (size_t)p * SPK_ELEMS;
#pragma unroll
  for (int mt = 0; mt < 2; ++mt)
#pragma unroll
    for (int r = 0; r < 4; ++r) {
      int o = o0 + wave * 32 + mt * 16 + lq * 4 + r;
      float bo = bias[o];
#pragma unroll
      for (int nt = 0; nt < 2; ++nt) {
        int n = n0 + nt * 16 + ln15;
        float vmem = 0.f;
#pragma unroll
        for (int t = 0; t < T_; ++t) {
          float y = (acc1[t][mt][nt][r] + acc2[t][mt][nt][r]) + bo;
          float v = vmem + (y - vmem) * 0.5f;
          bool s = (v >= 1.0f);
          sp[((size_t)(t * B_ + b) * C_ + o) * N_ + n] = s ? 1 : 0;
          vmem = s ? 0.f : v;
        }
      }
    }
}

// kv[t,b,h,d,e] = sum_n k*v (binary, exact). grid (H,B,T), block 256.
__global__ __launch_bounds__(256) void kv_kernel(
    const unsigned char* __restrict__ sk, const unsigned char* __restrict__ sv,
    float* __restrict__ kvout)
{
  __shared__ float Ksh[64][68];
  __shared__ float Vsh[64][68];
  const int tid = threadIdx.x;
  const int tx = tid & 15, ty = tid >> 4;
  const int tx4 = tx * 4, ty4 = ty * 4;
  const int h = blockIdx.x, b = blockIdx.y, t = blockIdx.z;
  const unsigned char* kb = sk + ((size_t)(t * B_ + b) * C_ + h * D_) * N_;
  const unsigned char* vb = sv + ((size_t)(t * B_ + b) * C_ + h * D_) * N_;
  float acc[4][4];
#pragma unroll
  for (int i = 0; i < 4; ++i)
#pragma unroll
    for (int j = 0; j < 4; ++j) acc[i][j] = 0.f;
  for (int nc = 0; nc < N_; nc += 64) {
    __syncthreads();
#pragma unroll
    for (int l = 0; l < 4; ++l) {
      int idx = tid + 256 * l;
      int dd = idx >> 4, n4 = (idx & 15) * 4;
      uchar4 ku = *(const uchar4*)&kb[(size_t)dd * N_ + nc + n4];
      uchar4 vu = *(const uchar4*)&vb[(size_t)dd * N_ + nc + n4];
      Ksh[n4 + 0][dd] = (float)ku.x; Ksh[n4 + 1][dd] = (float)ku.y;
      Ksh[n4 + 2][dd] = (float)ku.z; Ksh[n4 + 3][dd] = (float)ku.w;
      Vsh[n4 + 0][dd] = (float)vu.x; Vsh[n4 + 1][dd] = (float)vu.y;
      Vsh[n4 + 2][dd] = (float)vu.z; Vsh[n4 + 3][dd] = (float)vu.w;
    }
    __syncthreads();
#pragma unroll 8
    for (int nn = 0; nn < 64; ++nn) {
      float4 kvec = *(float4*)&Ksh[nn][ty4];
      float4 vvec = *(float4*)&Vsh[nn][tx4];
      FMA16(acc, kvec, vvec)
    }
  }
  float* o = kvout + ((size_t)(t * B_ + b) * H_ + h) * (D_ * D_);
#pragma unroll
  for (int i = 0; i < 4; ++i)
    *(float4*)&o[(ty4 + i) * D_ + tx4] =
        make_float4(acc[i][0], acc[i][1], acc[i][2], acc[i][3]);
}

// attn: Q@(KV)*0.125 -> LIF -> spikes as bf16 {0,1} at [t,b,n,c]
__global__ __launch_bounds__(256) void attn_lif_bf(
    const unsigned char* __restrict__ sq, const float* __restrict__ kv,
    unsigned short* __restrict__ sa)
{
  __shared__ float KVs[64][64];
  __shared__ float Qs[64][64];
  const int tid = threadIdx.x;
  const int tx = tid & 15, ty = tid >> 4;
  const int tx4 = tx * 4, ty4 = ty * 4;
  const int n0 = blockIdx.x * 64;
  const int h = blockIdx.y, b = blockIdx.z;
  float vm[4][4];
#pragma unroll
  for (int i = 0; i < 4; ++i)
#pragma unroll
    for (int j = 0; j < 4; ++j) vm[i][j] = 0.f;

  for (int t = 0; t < T_; ++t) {
    __syncthreads();
    const float* kvb = kv + ((size_t)(t * B_ + b) * H_ + h) * (D_ * D_);
    const unsigned char* qb = sq + ((size_t)(t * B_ + b) * C_ + h * D_) * N_ + n0;
#pragma unroll
    for (int l = 0; l < 4; ++l) {
      int idx = tid + 256 * l;
      int r = idx >> 4, c4 = (idx & 15) * 4;
      *(float4*)&KVs[r][c4] = *(const float4*)&kvb[r * D_ + c4];
      uchar4 qu = *(const uchar4*)&qb[(size_t)r * N_ + c4];
      *(float4*)&Qs[r][c4] =
          make_float4((float)qu.x, (float)qu.y, (float)qu.z, (float)qu.w);
    }
    __syncthreads();

    float acc[4][4];
#pragma unroll
    for (int i = 0; i < 4; ++i)
#pragma unroll
      for (int j = 0; j < 4; ++j) acc[i][j] = 0.f;
#pragma unroll 8
    for (int dd = 0; dd < 64; ++dd) {
      float4 qv  = *(float4*)&Qs[dd][ty4];
      float4 kvv = *(float4*)&KVs[dd][tx4];
      FMA16(acc, qv, kvv)
    }

    unsigned short sb[4][4];   // [i=n][j=c]
#pragma unroll
    for (int j = 0; j < 4; ++j)
#pragma unroll
      for (int i = 0; i < 4; ++i) {
        float y = acc[i][j] * 0.125f;
        float v = vm[i][j];
        v = v + (y - v) * 0.5f;
        bool s = (v >= 1.0f);
        sb[i][j] = s ? 0x3F80 : 0;
        vm[i][j] = s ? 0.f : v;
      }
#pragma unroll
    for (int i = 0; i < 4; ++i) {
      ushort4 st = make_ushort4(sb[i][0], sb[i][1], sb[i][2], sb[i][3]);
      *(ushort4*)&sa[((size_t)(t * B_ + b) * N_ + n0 + ty4 + i) * C_ + h * D_ + tx4] = st;
    }
  }
}

// proj GEMM (W digits x exact bf16 spikes) + connecting LIF. d_out fp32.
// grid: x = 4 o-tiles * 32 n-tiles = 128, y = b(16)
__global__ __launch_bounds__(256) void proj_mfma(
    const unsigned short* __restrict__ wb, const unsigned short* __restrict__ sa,
    const float* __restrict__ bp, const float* __restrict__ x,
    float* __restrict__ out)
{
  // LDS: WS[3][128][32] (24KB) + SS[4][32][32] (8KB)
  __shared__ __align__(16) char lds[32768];
  const int tid = threadIdx.x;
  const int lane = tid & 63, wave = tid >> 6;
  const int ln15 = lane & 15, lq = lane >> 4;
  const int ot = blockIdx.x & 3, ntb = blockIdx.x >> 2;
  const int o0 = ot * 128, n0 = ntb * 32;
  const int b = blockIdx.y;

  const unsigned short* gsrc[8];
#pragma unroll
  for (int i = 0; i < 8; ++i) {
    int u = i * 256 + tid;
    if (u < 1536) {
      int s = u >> 9, rem = u & 511;
      int row = rem >> 2, pc = rem & 3;
      int lc = pc ^ ((row >> 1) & 3);
      gsrc[i] = wb + (((size_t)(3 * 3 + s)) << 18) + (size_t)(o0 + row) * C_ + lc * 8;
    } else {
      int v = u - 1536;
      int t = v >> 7, rem2 = v & 127;
      int row = rem2 >> 2, pc = rem2 & 3;
      int lc = pc ^ ((row >> 1) & 3);
      gsrc[i] = sa + ((size_t)((t * B_ + b) * N_ + n0 + row)) * C_ + lc * 8;
    }
  }

  f32x4 acc1[T_][2][2], acc2[T_][2][2];
#pragma unroll
  for (int t = 0; t < T_; ++t)
#pragma unroll
    for (int mt = 0; mt < 2; ++mt)
#pragma unroll
      for (int nt = 0; nt < 2; ++nt) {
        acc1[t][mt][nt] = (f32x4){0.f, 0.f, 0.f, 0.f};
        acc2[t][mt][nt] = (f32x4){0.f, 0.f, 0.f, 0.f};
      }

  int offA[3][2], offB[2];
#pragma unroll
  for (int s = 0; s < 3; ++s)
#pragma unroll
    for (int mt = 0; mt < 2; ++mt) {
      int r = wave * 32 + mt * 16 + ln15;
      offA[s][mt] = s * 8192 + r * 64 + ((lq ^ ((r >> 1) & 3)) << 4);
    }
#pragma unroll
  for (int nt = 0; nt < 2; ++nt) {
    int n = nt * 16 + ln15;
    offB[nt] = 24576 + n * 64 + ((lq ^ ((n >> 1) & 3)) << 4);
  }

  for (int kk = 0; kk < 16; ++kk) {
#pragma unroll
    for (int i = 0; i < 8; ++i)
      GLD16(gsrc[i], i * 4096 + (tid & 192) * 16);
    __syncthreads();

    short8 wa[3][2];
#pragma unroll
    for (int s = 0; s < 3; ++s)
#pragma unroll
      for (int mt = 0; mt < 2; ++mt)
        wa[s][mt] = *(const short8*)&lds[offA[s][mt]];

#pragma unroll
    for (int t = 0; t < T_; ++t) {
      short8 xb[2];
#pragma unroll
      for (int nt = 0; nt < 2; ++nt)
        xb[nt] = *(const short8*)&lds[offB[nt] + t * 2048];
#pragma unroll
      for (int mt = 0; mt < 2; ++mt)
#pragma unroll
        for (int nt = 0; nt < 2; ++nt) {
          acc1[t][mt][nt] = __builtin_amdgcn_mfma_f32_16x16x32_bf16(
              wa[0][mt], xb[nt], acc1[t][mt][nt], 0, 0, 0);
          acc2[t][mt][nt] = __builtin_amdgcn_mfma_f32_16x16x32_bf16(
              wa[1][mt], xb[nt], acc2[t][mt][nt], 0, 0, 0);
          acc2[t][mt][nt] = __builtin_amdgcn_mfma_f32_16x16x32_bf16(
              wa[2][mt], xb[nt], acc2[t][mt][nt], 0, 0, 0);
        }
    }
    __syncthreads();
#pragma unroll
    for (int i = 0; i < 8; ++i) gsrc[i] += 32;
  }

  // epilogue: connecting LIF with identity shortcut
#pragma unroll
  for (int mt = 0; mt < 2; ++mt)
#pragma unroll
    for (int r = 0; r < 4; ++r) {
      int o = o0 + wave * 32 + mt * 16 + lq * 4 + r;
      float bo = bp[o];
#pragma unroll
      for (int nt = 0; nt < 2; ++nt) {
        int n = n0 + nt * 16 + ln15;
        float vmem = 0.f;
#pragma unroll
        for (int t = 0; t < T_; ++t) {
          size_t base = ((size_t)(t * B_ + b) * C_ + o) * N_ + n;
          float xv = x[base];
          float pv = (acc1[t][mt][nt][r] + acc2[t][mt][nt][r]) + bo;
          float v = vmem + ((pv + xv) - vmem) * 0.5f;
          bool s = (v >= 1.0f);
          out[base] = s ? 1.0f : 0.0f;
          vmem = s ? 0.f : v;
        }
      }
    }
}

// ===========================================================================
// FALLBACK PATH (round-1 fp32 VALU kernels, used if ws_size is too small)
// ===========================================================================
__global__ __launch_bounds__(256) void transpose_w(
    const float* __restrict__ w0, const float* __restrict__ w1,
    const float* __restrict__ w2, const float* __restrict__ w3,
    float* __restrict__ wt_all)
{
  __shared__ float tile[32][33];
  const float* src = (blockIdx.z == 0) ? w0 : (blockIdx.z == 1) ? w1
                   : (blockIdx.z == 2) ? w2 : w3;
  float* dst = wt_all + (size_t)blockIdx.z * C_ * C_;
  const int tx = threadIdx.x, ty = threadIdx.y;
  const int o0 = blockIdx.y * 32, c0 = blockIdx.x * 32;
#pragma unroll
  for (int k = 0; k < 4; ++k)
    tile[ty + k * 8][tx] = src[(size_t)(o0 + ty + k * 8) * C_ + c0 + tx];
  __syncthreads();
#pragma unroll
  for (int k = 0; k < 4; ++k)
    dst[(size_t)(c0 + ty + k * 8) * C_ + o0 + tx] = tile[tx][ty + k * 8];
}

__global__ __launch_bounds__(256) void qkv_lif_old(
    const float* __restrict__ x, const float* __restrict__ wt_all,
    const float* __restrict__ bq, const float* __restrict__ bk,
    const float* __restrict__ bv, unsigned char* __restrict__ spikes_base)
{
  __shared__ float Ws[32][64];
  __shared__ float Xs[T_][32][64];
  const int tid = threadIdx.x;
  const int tx = tid & 15, ty = tid >> 4;
  const int tx4 = tx * 4, ty4 = ty * 4;
  const int n0 = blockIdx.x * 64;
  const int o0 = (blockIdx.y & 7) * 64;
  const int b  = blockIdx.y >> 3;
  const int p  = blockIdx.z;
  const float* wt = wt_all + (size_t)p * C_ * C_;
  const float* bias = (p == 0) ? bq : (p == 1) ? bk : bv;
  unsigned char* sp = spikes_base + (size_t)p * SPK_ELEMS;
  float acc[T_][4][4];
#pragma unroll
  for (int t = 0; t < T_; ++t)
#pragma unroll
    for (int i = 0; i < 4; ++i)
#pragma unroll
      for (int j = 0; j < 4; ++j) acc[t][i][j] = 0.f;
  for (int kc = 0; kc < C_; kc += 32) {
    __syncthreads();
#pragma unroll
    for (int l = 0; l < 2; ++l) {
      int idx = tid + 256 * l;
      int r = idx >> 4, c4 = (idx & 15) * 4;
      *(float4*)&Ws[r][c4] = *(const float4*)&wt[(size_t)(kc + r) * C_ + o0 + c4];
    }
#pragma unroll
    for (int t = 0; t < T_; ++t) {
      const float* xb = x + ((size_t)(t * B_ + b) * C_ + kc) * N_ + n0;
#pragma unroll
      for (int l = 0; l < 2; ++l) {
        int idx = tid + 256 * l;
        int r = idx >> 4, c4 = (idx & 15) * 4;
        *(float4*)&Xs[t][r][c4] = *(const float4*)&xb[(size_t)r * N_ + c4];
      }
    }
    __syncthreads();
#pragma unroll 4
    for (int kk = 0; kk < 32; ++kk) {
      float4 wv = *(float4*)&Ws[kk][ty4];
#pragma unroll
      for (int t = 0; t < T_; ++t) {
        float4 xv = *(float4*)&Xs[t][kk][tx4];
        FMA16(acc[t], wv, xv)
      }
    }
  }
  float4 b4 = *(const float4*)&bias[o0 + ty4];
  float barr[4] = {b4.x, b4.y, b4.z, b4.w};
  float vm[4][4];
#pragma unroll
  for (int i = 0; i < 4; ++i)
#pragma unroll
    for (int j = 0; j < 4; ++j) vm[i][j] = 0.f;
#pragma unroll
  for (int t = 0; t < T_; ++t) {
#pragma unroll
    for (int i = 0; i < 4; ++i) {
      unsigned char sj[4];
#pragma unroll
      for (int j = 0; j < 4; ++j) {
        float y = acc[t][i][j] + barr[i];
        float v = vm[i][j];
        v = v + (y - v) * 0.5f;
        bool s = (v >= 1.0f);
        sj[j] = s ? 1 : 0;
        vm[i][j] = s ? 0.f : v;
      }
      *(uchar4*)&sp[((size_t)(t * B_ + b) * C_ + o0 + ty4 + i) * N_ + n0 + tx4] =
          make_uchar4(sj[0], sj[1], sj[2], sj[3]);
    }
  }
}

__global__ __launch_bounds__(256) void attn_lif_old(
    const unsigned char* __restrict__ sq, const float* __restrict__ kv,
    unsigned char* __restrict__ sa)
{
  __shared__ float KVs[64][64];
  __shared__ float Qs[64][64];
  const int tid = threadIdx.x;
  const int tx = tid & 15, ty = tid >> 4;
  const int tx4 = tx * 4, ty4 = ty * 4;
  const int n0 = blockIdx.x * 64;
  const int h = blockIdx.y, b = blockIdx.z;
  float vm[4][4];
#pragma unroll
  for (int i = 0; i < 4; ++i)
#pragma unroll
    for (int j = 0; j < 4; ++j) vm[i][j] = 0.f;
  for (int t = 0; t < T_; ++t) {
    __syncthreads();
    const float* kvb = kv + ((size_t)(t * B_ + b) * H_ + h) * (D_ * D_);
    const unsigned char* qb = sq + ((size_t)(t * B_ + b) * C_ + h * D_) * N_ + n0;
#pragma unroll
    for (int l = 0; l < 4; ++l) {
      int idx = tid + 256 * l;
      int r = idx >> 4, c4 = (idx & 15) * 4;
      *(float4*)&KVs[r][c4] = *(const float4*)&kvb[r * D_ + c4];
      uchar4 qu = *(const uchar4*)&qb[(size_t)r * N_ + c4];
      *(float4*)&Qs[r][c4] =
          make_float4((float)qu.x, (float)qu.y, (float)qu.z, (float)qu.w);
    }
    __syncthreads();
    float acc[4][4];
#pragma unroll
    for (int i = 0; i < 4; ++i)
#pragma unroll
      for (int j = 0; j < 4; ++j) acc[i][j] = 0.f;
#pragma unroll 8
    for (int dd = 0; dd < 64; ++dd) {
      float4 qv  = *(float4*)&Qs[dd][ty4];
      float4 kvv = *(float4*)&KVs[dd][tx4];
      FMA16(acc, qv, kvv)
    }
#pragma unroll
    for (int j = 0; j < 4; ++j) {
      unsigned char si[4];
#pragma unroll
      for (int i = 0; i < 4; ++i) {
        float y = acc[i][j] * 0.125f;
        float v = vm[i][j];
        v = v + (y - v) * 0.5f;
        bool s = (v >= 1.0f);
        si[i] = s ? 1 : 0;
        vm[i][j] = s ? 0.f : v;
      }
      *(uchar4*)&sa[((size_t)(t * B_ + b) * C_ + h * D_ + tx4 + j) * N_ + n0 + ty4] =
          make_uchar4(si[0], si[1], si[2], si[3]);
    }
  }
}

__global__ __launch_bounds__(256) void proj_conn_old(
    const float* __restrict__ x, const float* __restrict__ wt_all,
    const float* __restrict__ bp, const unsigned char* __restrict__ sa,
    float* __restrict__ out)
{
  __shared__ float Ws[32][64];
  __shared__ float Ss[T_][32][64];
  const int tid = threadIdx.x;
  const int tx = tid & 15, ty = tid >> 4;
  const int tx4 = tx * 4, ty4 = ty * 4;
  const int n0 = blockIdx.x * 64;
  const int o0 = (blockIdx.y & 7) * 64;
  const int b  = blockIdx.y >> 3;
  const float* wt = wt_all + 3ull * C_ * C_;
  float acc[T_][4][4];
#pragma unroll
  for (int t = 0; t < T_; ++t)
#pragma unroll
    for (int i = 0; i < 4; ++i)
#pragma unroll
      for (int j = 0; j < 4; ++j) acc[t][i][j] = 0.f;
  for (int kc = 0; kc < C_; kc += 32) {
    __syncthreads();
#pragma unroll
    for (int l = 0; l < 2; ++l) {
      int idx = tid + 256 * l;
      int r = idx >> 4, c4 = (idx & 15) * 4;
      *(float4*)&Ws[r][c4] = *(const float4*)&wt[(size_t)(kc + r) * C_ + o0 + c4];
    }
#pragma unroll
    for (int t = 0; t < T_; ++t) {
      const unsigned char* sb = sa + ((size_t)(t * B_ + b) * C_ + kc) * N_ + n0;
#pragma unroll
      for (int l = 0; l < 2; ++l) {
        int idx = tid + 256 * l;
        int r = idx >> 4, c4 = (idx & 15) * 4;
        uchar4 su = *(const uchar4*)&sb[(size_t)r * N_ + c4];
        *(float4*)&Ss[t][r][c4] =
            make_float4((float)su.x, (float)su.y, (float)su.z, (float)su.w);
      }
    }
    __syncthreads();
#pragma unroll 4
    for (int kk = 0; kk < 32; ++kk) {
      float4 wv = *(float4*)&Ws[kk][ty4];
#pragma unroll
      for (int t = 0; t < T_; ++t) {
        float4 sv = *(float4*)&Ss[t][kk][tx4];
        FMA16(acc[t], wv, sv)
      }
    }
  }
  float4 b4 = *(const float4*)&bp[o0 + ty4];
  float barr[4] = {b4.x, b4.y, b4.z, b4.w};
  float vm[4][4];
#pragma unroll
  for (int i = 0; i < 4; ++i)
#pragma unroll
    for (int j = 0; j < 4; ++j) vm[i][j] = 0.f;
#pragma unroll
  for (int t = 0; t < T_; ++t) {
#pragma unroll
    for (int i = 0; i < 4; ++i) {
      size_t base = ((size_t)(t * B_ + b) * C_ + o0 + ty4 + i) * N_ + n0 + tx4;
      float4 xv = *(const float4*)&x[base];
      float xarr[4] = {xv.x, xv.y, xv.z, xv.w};
      float oarr[4];
#pragma unroll
      for (int j = 0; j < 4; ++j) {
        float pv = acc[t][i][j] + barr[i];
        float v = vm[i][j];
        v = v + ((pv + xarr[j]) - v) * 0.5f;
        bool s = (v >= 1.0f);
        oarr[j] = s ? 1.0f : 0.0f;
        vm[i][j] = s ? 0.f : v;
      }
      *(float4*)&out[base] = make_float4(oarr[0], oarr[1], oarr[2], oarr[3]);
    }
  }
}

// ---------------------------------------------------------------------------
extern "C" void kernel_launch(void* const* d_in, const int* in_sizes, int n_in,
                              void* d_out, int out_size, void* d_ws, size_t ws_size,
                              hipStream_t stream)
{
  const float* x  = (const float*)d_in[0];
  const float* Wq = (const float*)d_in[1];
  const float* bq = (const float*)d_in[2];
  const float* Wk = (const float*)d_in[3];
  const float* bk = (const float*)d_in[4];
  const float* Wv = (const float*)d_in[5];
  const float* bv = (const float*)d_in[6];
  const float* Wp = (const float*)d_in[7];
  const float* bp = (const float*)d_in[8];
  (void)in_sizes; (void)n_in; (void)out_size;

  unsigned char* ws = (unsigned char*)d_ws;
  float* out = (float*)d_out;

  if (ws_size >= NEW_WS_NEED) {
    unsigned char* sq = ws;
    unsigned char* sk = ws + SPK_ELEMS;
    unsigned char* sv = ws + 2 * SPK_ELEMS;
    float* kvbuf = (float*)(ws + KV_OFF_N);
    unsigned short* wb = (unsigned short*)(ws + WB_OFF_N);
    unsigned short* xs = (unsigned short*)(ws + XS_OFF_N);
    unsigned short* sa = xs;  // alias digit-0 region (xs dead before attn writes)

    convert_w<<<4096, 256, 0, stream>>>(Wq, Wk, Wv, Wp, wb);
    convert_x<<<dim3(32, 16, 64), dim3(32, 8), 0, stream>>>(x, xs);
    qkv_mfma<<<dim3(128, 16, 3), 256, 0, stream>>>(wb, xs, bq, bk, bv, ws);
    kv_kernel<<<dim3(8, 16, 4), 256, 0, stream>>>(sk, sv, kvbuf);
    attn_lif_bf<<<dim3(16, 8, 16), 256, 0, stream>>>(sq, kvbuf, sa);
    proj_mfma<<<dim3(128, 16), 256, 0, stream>>>(wb, sa, bp, x, out);
  } else {
    unsigned char* sq = ws;
    unsigned char* sk = ws + SPK_ELEMS;
    unsigned char* sv = ws + 2 * SPK_ELEMS;
    unsigned char* sa = ws + SA_OFF_O;
    float* kvbuf = (float*)(ws + KV_OFF_O);
    float* wt    = (float*)(ws + WT_OFF_O);
    transpose_w<<<dim3(16, 16, 4), dim3(32, 8), 0, stream>>>(Wq, Wk, Wv, Wp, wt);
    qkv_lif_old<<<dim3(16, 128, 3), 256, 0, stream>>>(x, wt, bq, bk, bv, ws);
    kv_kernel<<<dim3(8, 16, 4), 256, 0, stream>>>(sk, sv, kvbuf);
    attn_lif_old<<<dim3(16, 8, 16), 256, 0, stream>>>(sq, kvbuf, sa);
    proj_conn_old<<<dim3(16, 128), 256, 0, stream>>>(x, wt, bp, sa, out);
  }
}

// Round 3
// 1067.117 us; speedup vs baseline: 1.7485x; 1.3952x over previous
//
#include <hip/hip_runtime.h>

// Problem constants
#define T_ 4
#define B_ 16
#define C_ 512
#define N_ 1024
#define H_ 8
#define D_ 64
#define SPK_ELEMS (33554432ull)   // T*B*C*N

typedef short short8 __attribute__((ext_vector_type(8)));
typedef _Float16 half8v __attribute__((ext_vector_type(8)));
typedef _Float16 half4v __attribute__((ext_vector_type(4)));
typedef float f32x4 __attribute__((ext_vector_type(4)));

// ---------------- workspace layout (bytes) ----------------
// sq:  [0, 33554432)            uint8 q spikes  [t,b,n,c]  (TRANSPOSED)
// sk:  [33554432, 67108864)     uint8 k spikes  [t,b,c,n]
// sv:  [67108864, 100663296)    uint8 v spikes  [t,b,c,n]
// kv:  [100663296, 109051904)   fp32  [t,b,h,d,e]
// wb:  [109051904, 115343360)   bf16  [p=4][digit=3][512][512]
// xs:  [115343360, 316669952)   bf16  [digit=3][t][b][n][c]
// sa:  aliases xs digit-0 region (xs dead before attn writes it)
#define NEW_WS_NEED 316669952ull
#define KV_OFF_N  100663296ull
#define WB_OFF_N  109051904ull
#define XS_OFF_N  115343360ull

#define FMA16(A, av, bv) \
  A[0][0] = fmaf(av.x, bv.x, A[0][0]); A[0][1] = fmaf(av.x, bv.y, A[0][1]); \
  A[0][2] = fmaf(av.x, bv.z, A[0][2]); A[0][3] = fmaf(av.x, bv.w, A[0][3]); \
  A[1][0] = fmaf(av.y, bv.x, A[1][0]); A[1][1] = fmaf(av.y, bv.y, A[1][1]); \
  A[1][2] = fmaf(av.y, bv.z, A[1][2]); A[1][3] = fmaf(av.y, bv.w, A[1][3]); \
  A[2][0] = fmaf(av.z, bv.x, A[2][0]); A[2][1] = fmaf(av.z, bv.y, A[2][1]); \
  A[2][2] = fmaf(av.z, bv.z, A[2][2]); A[2][3] = fmaf(av.z, bv.w, A[2][3]); \
  A[3][0] = fmaf(av.w, bv.x, A[3][0]); A[3][1] = fmaf(av.w, bv.y, A[3][1]); \
  A[3][2] = fmaf(av.w, bv.z, A[3][2]); A[3][3] = fmaf(av.w, bv.w, A[3][3]);

__device__ __forceinline__ unsigned short bf_rne(float f) {
  unsigned u = __float_as_uint(f);
  unsigned r = (u + 0x7FFFu + ((u >> 16) & 1u)) >> 16;
  return (unsigned short)r;
}
__device__ __forceinline__ float bf2f(unsigned short h) {
  return __uint_as_float(((unsigned)h) << 16);
}

#define GLD16(gp, loff) \
  __builtin_amdgcn_global_load_lds( \
      (const __attribute__((address_space(1))) void*)(gp), \
      (__attribute__((address_space(3))) void*)(lds + (loff)), 16, 0, 0)

// ---------------------------------------------------------------------------
// W [4 mats][512][512] fp32 -> wb [p][3][512][512] bf16 digits
// ---------------------------------------------------------------------------
__global__ __launch_bounds__(256) void convert_w(
    const float* __restrict__ w0, const float* __restrict__ w1,
    const float* __restrict__ w2, const float* __restrict__ w3,
    unsigned short* __restrict__ wb)
{
  int idx = blockIdx.x * 256 + threadIdx.x;      // 0..1048575
  int p = idx >> 18, rem = idx & 262143;
  const float* src = (p == 0) ? w0 : (p == 1) ? w1 : (p == 2) ? w2 : w3;
  float v = src[rem];
  unsigned short h1 = bf_rne(v);
  float r1 = v - bf2f(h1);
  unsigned short h2 = bf_rne(r1);
  float r2 = r1 - bf2f(h2);
  unsigned short h3 = bf_rne(r2);
  size_t base = ((size_t)(p * 3)) << 18;
  wb[base + rem] = h1;
  wb[base + 262144 + rem] = h2;
  wb[base + 524288 + rem] = h3;
}

// ---------------------------------------------------------------------------
// x [t,b,c,n] fp32 -> xs [digit][t,b,n,c] bf16 (transposed inner dims)
// ---------------------------------------------------------------------------
__global__ __launch_bounds__(256) void convert_x(
    const float* __restrict__ x, unsigned short* __restrict__ xs)
{
  __shared__ float tile[32][33];
  const int tb = blockIdx.z;
  const int c0 = blockIdx.y * 32, n0 = blockIdx.x * 32;
  const int tx = threadIdx.x, ty = threadIdx.y;
  const float* src = x + ((size_t)tb * C_ + c0) * N_ + n0;
#pragma unroll
  for (int k = 0; k < 4; ++k)
    tile[ty + 8 * k][tx] = src[(size_t)(ty + 8 * k) * N_ + tx];
  __syncthreads();
#pragma unroll
  for (int k = 0; k < 4; ++k) {
    int r = ty + 8 * k;                       // n-offset within tile
    float v = tile[tx][r];                    // element (c=c0+tx, n=n0+r)
    unsigned short h1 = bf_rne(v);
    float r1 = v - bf2f(h1);
    unsigned short h2 = bf_rne(r1);
    float r2 = r1 - bf2f(h2);
    unsigned short h3 = bf_rne(r2);
    size_t o = ((size_t)tb * N_ + n0 + r) * C_ + c0 + tx;
    xs[o] = h1;
    xs[o + 33554432ull] = h2;
    xs[o + 67108864ull] = h3;
  }
}

// ---------------------------------------------------------------------------
// Fused q/k/v GEMM (6-product bf16 digit MFMA, single fp32 accumulator) + LIF.
// Block tile 128o x 32n x 4t.  grid (12=(ot|p), 32=ntb, 16=b) — (ot,p)
// innermost so all 12 consumers of an xs slab are dispatch-adjacent (L3 reuse).
// q spikes written TRANSPOSED [t,b,n,c]; k,v spikes [t,b,c,n].
// ---------------------------------------------------------------------------
__global__ __launch_bounds__(256) void qkv_mfma(
    const unsigned short* __restrict__ wb, const unsigned short* __restrict__ xs,
    const float* __restrict__ bq, const float* __restrict__ bk,
    const float* __restrict__ bv, unsigned char* __restrict__ spikes_base)
{
  // LDS: WS[3][128][32] bf16 (24KB) + XS[3][4][32][32] bf16 (24KB)
  __shared__ __align__(16) char lds[49152];
  const int tid = threadIdx.x;
  const int lane = tid & 63, wave = tid >> 6;
  const int ln15 = lane & 15, lq = lane >> 4;
  const int ot = blockIdx.x & 3, p = blockIdx.x >> 2;
  const int ntb = blockIdx.y, b = blockIdx.z;
  const int o0 = ot * 128, n0 = ntb * 32;

  // staging sources: 12 x 16B per thread per k-iter (48KB total)
  const unsigned short* gsrc[12];
#pragma unroll
  for (int i = 0; i < 12; ++i) {
    int u = i * 256 + tid;
    if (u < 1536) {               // W region
      int s = u >> 9, rem = u & 511;
      int row = rem >> 2, pc = rem & 3;
      int lc = pc ^ ((row >> 1) & 3);
      gsrc[i] = wb + (((size_t)(p * 3 + s)) << 18) + (size_t)(o0 + row) * C_ + lc * 8;
    } else {                      // X region
      int v = u - 1536;
      int s = v >> 9, rem = v & 511;
      int t = rem >> 7, rem2 = rem & 127;
      int row = rem2 >> 2, pc = rem2 & 3;
      int lc = pc ^ ((row >> 1) & 3);
      gsrc[i] = xs + ((size_t)s * 33554432ull) +
                ((size_t)((t * B_ + b) * N_ + n0 + row)) * C_ + lc * 8;
    }
  }

  f32x4 acc[T_][2][2];
#pragma unroll
  for (int t = 0; t < T_; ++t)
#pragma unroll
    for (int mt = 0; mt < 2; ++mt)
#pragma unroll
      for (int nt = 0; nt < 2; ++nt)
        acc[t][mt][nt] = (f32x4){0.f, 0.f, 0.f, 0.f};

  int offA[3][2], offB[3][2];
#pragma unroll
  for (int s = 0; s < 3; ++s) {
#pragma unroll
    for (int mt = 0; mt < 2; ++mt) {
      int r = wave * 32 + mt * 16 + ln15;
      offA[s][mt] = s * 8192 + r * 64 + ((lq ^ ((r >> 1) & 3)) << 4);
    }
#pragma unroll
    for (int nt = 0; nt < 2; ++nt) {
      int n = nt * 16 + ln15;
      offB[s][nt] = 24576 + s * 8192 + n * 64 + ((lq ^ ((n >> 1) & 3)) << 4);
    }
  }

  for (int kk = 0; kk < 16; ++kk) {
#pragma unroll
    for (int i = 0; i < 12; ++i)
      GLD16(gsrc[i], i * 4096 + (tid & 192) * 16);
    __syncthreads();

    short8 wa[3][2];
#pragma unroll
    for (int s = 0; s < 3; ++s)
#pragma unroll
      for (int mt = 0; mt < 2; ++mt)
        wa[s][mt] = *(const short8*)&lds[offA[s][mt]];

#pragma unroll
    for (int t = 0; t < T_; ++t) {
      short8 xb[3][2];
#pragma unroll
      for (int s = 0; s < 3; ++s)
#pragma unroll
        for (int nt = 0; nt < 2; ++nt)
          xb[s][nt] = *(const short8*)&lds[offB[s][nt] + t * 2048];
#pragma unroll
      for (int mt = 0; mt < 2; ++mt)
#pragma unroll
        for (int nt = 0; nt < 2; ++nt) {
          f32x4 a = acc[t][mt][nt];
          a = __builtin_amdgcn_mfma_f32_16x16x32_bf16(wa[0][mt], xb[1][nt], a, 0, 0, 0);
          a = __builtin_amdgcn_mfma_f32_16x16x32_bf16(wa[1][mt], xb[0][nt], a, 0, 0, 0);
          a = __builtin_amdgcn_mfma_f32_16x16x32_bf16(wa[0][mt], xb[2][nt], a, 0, 0, 0);
          a = __builtin_amdgcn_mfma_f32_16x16x32_bf16(wa[2][mt], xb[0][nt], a, 0, 0, 0);
          a = __builtin_amdgcn_mfma_f32_16x16x32_bf16(wa[1][mt], xb[1][nt], a, 0, 0, 0);
          a = __builtin_amdgcn_mfma_f32_16x16x32_bf16(wa[0][mt], xb[0][nt], a, 0, 0, 0);
          acc[t][mt][nt] = a;
        }
    }
    __syncthreads();
#pragma unroll
    for (int i = 0; i < 12; ++i) gsrc[i] += 32;
  }

  // epilogue: bias + LIF over t
  const float* bias = (p == 0) ? bq : (p == 1) ? bk : bv;
  if (p == 0) {
    // q: transposed store [t,b,n,c], contiguous uchar4 along c
    unsigned char* spq = spikes_base;
#pragma unroll
    for (int mt = 0; mt < 2; ++mt) {
      int obase = o0 + wave * 32 + mt * 16 + lq * 4;
      float b4[4] = {bias[obase], bias[obase + 1], bias[obase + 2], bias[obase + 3]};
#pragma unroll
      for (int nt = 0; nt < 2; ++nt) {
        int n = n0 + nt * 16 + ln15;
        float vm[4] = {0.f, 0.f, 0.f, 0.f};
#pragma unroll
        for (int t = 0; t < T_; ++t) {
          unsigned char sj[4];
#pragma unroll
          for (int r = 0; r < 4; ++r) {
            float y = acc[t][mt][nt][r] + b4[r];
            float v = vm[r] + (y - vm[r]) * 0.5f;
            bool s = (v >= 1.0f);
            sj[r] = s ? 1 : 0;
            vm[r] = s ? 0.f : v;
          }
          *(uchar4*)&spq[((size_t)(t * B_ + b) * N_ + n) * C_ + obase] =
              make_uchar4(sj[0], sj[1], sj[2], sj[3]);
        }
      }
    }
  } else {
    unsigned char* sp = spikes_base + (size_t)p * SPK_ELEMS;
#pragma unroll
    for (int mt = 0; mt < 2; ++mt)
#pragma unroll
      for (int r = 0; r < 4; ++r) {
        int o = o0 + wave * 32 + mt * 16 + lq * 4 + r;
        float bo = bias[o];
#pragma unroll
        for (int nt = 0; nt < 2; ++nt) {
          int n = n0 + nt * 16 + ln15;
          float vmem = 0.f;
#pragma unroll
          for (int t = 0; t < T_; ++t) {
            float y = acc[t][mt][nt][r] + bo;
            float v = vmem + (y - vmem) * 0.5f;
            bool s = (v >= 1.0f);
            sp[((size_t)(t * B_ + b) * C_ + o) * N_ + n] = s ? 1 : 0;
            vmem = s ? 0.f : v;
          }
        }
      }
  }
}

// ---------------------------------------------------------------------------
// kv[t,b,h,d,e] = sum_n k*v (binary, exact). grid (H,B,T), block 256.
// ---------------------------------------------------------------------------
__global__ __launch_bounds__(256) void kv_kernel(
    const unsigned char* __restrict__ sk, const unsigned char* __restrict__ sv,
    float* __restrict__ kvout)
{
  __shared__ float Ksh[64][68];
  __shared__ float Vsh[64][68];
  const int tid = threadIdx.x;
  const int tx = tid & 15, ty = tid >> 4;
  const int tx4 = tx * 4, ty4 = ty * 4;
  const int h = blockIdx.x, b = blockIdx.y, t = blockIdx.z;
  const unsigned char* kb = sk + ((size_t)(t * B_ + b) * C_ + h * D_) * N_;
  const unsigned char* vb = sv + ((size_t)(t * B_ + b) * C_ + h * D_) * N_;
  float acc[4][4];
#pragma unroll
  for (int i = 0; i < 4; ++i)
#pragma unroll
    for (int j = 0; j < 4; ++j) acc[i][j] = 0.f;
  for (int nc = 0; nc < N_; nc += 64) {
    __syncthreads();
#pragma unroll
    for (int l = 0; l < 4; ++l) {
      int idx = tid + 256 * l;
      int dd = idx >> 4, n4 = (idx & 15) * 4;
      uchar4 ku = *(const uchar4*)&kb[(size_t)dd * N_ + nc + n4];
      uchar4 vu = *(const uchar4*)&vb[(size_t)dd * N_ + nc + n4];
      Ksh[n4 + 0][dd] = (float)ku.x; Ksh[n4 + 1][dd] = (float)ku.y;
      Ksh[n4 + 2][dd] = (float)ku.z; Ksh[n4 + 3][dd] = (float)ku.w;
      Vsh[n4 + 0][dd] = (float)vu.x; Vsh[n4 + 1][dd] = (float)vu.y;
      Vsh[n4 + 2][dd] = (float)vu.z; Vsh[n4 + 3][dd] = (float)vu.w;
    }
    __syncthreads();
#pragma unroll 8
    for (int nn = 0; nn < 64; ++nn) {
      float4 kvec = *(float4*)&Ksh[nn][ty4];
      float4 vvec = *(float4*)&Vsh[nn][tx4];
      FMA16(acc, kvec, vvec)
    }
  }
  float* o = kvout + ((size_t)(t * B_ + b) * H_ + h) * (D_ * D_);
#pragma unroll
  for (int i = 0; i < 4; ++i)
    *(float4*)&o[(ty4 + i) * D_ + tx4] =
        make_float4(acc[i][0], acc[i][1], acc[i][2], acc[i][3]);
}

// ---------------------------------------------------------------------------
// attn: out[e][n] = sum_d kvT[e][d] * q[n][d], *0.125, LIF over t.
// f16 MFMA — q in {0,1}, kv ints <=1024: exact. Writes sa bf16 [t,b,n,c].
// grid (8 n-tiles of 128, H, B), block 256 (wave w = e-tile).
// ---------------------------------------------------------------------------
__global__ __launch_bounds__(256) void attn_mfma(
    const unsigned char* __restrict__ sq2, const float* __restrict__ kv,
    unsigned short* __restrict__ sa)
{
  __shared__ _Float16 Qs[128 * 72];    // [n][d] pitch 72
  __shared__ _Float16 KVT[64 * 72];    // [e][d] pitch 72
  const int tid = threadIdx.x;
  const int lane = tid & 63, wave = tid >> 6;   // wave = e-tile
  const int ln15 = lane & 15, lq = lane >> 4;
  const int n0 = blockIdx.x * 128;
  const int h = blockIdx.y, b = blockIdx.z;

  f32x4 vm[8];
#pragma unroll
  for (int nt = 0; nt < 8; ++nt) vm[nt] = (f32x4){0.f, 0.f, 0.f, 0.f};

  for (int t = 0; t < T_; ++t) {
    __syncthreads();
    const float* kvb = kv + ((size_t)(t * B_ + b) * H_ + h) * (D_ * D_);
#pragma unroll
    for (int l = 0; l < 16; ++l) {
      int idx = l * 256 + tid;
      int e = idx & 63, d = idx >> 6;
      KVT[e * 72 + d] = (_Float16)kvb[d * 64 + e];   // ints <=1024: exact
    }
    const unsigned char* qb = sq2 + ((size_t)(t * B_ + b) * N_ + n0) * C_ + h * D_;
#pragma unroll
    for (int l = 0; l < 8; ++l) {
      int idx = l * 256 + tid;
      int n = idx >> 4, d4 = (idx & 15) * 4;
      uchar4 qu = *(const uchar4*)&qb[(size_t)n * C_ + d4];
      half4v hv;
      hv.x = qu.x ? (_Float16)1.0f : (_Float16)0.0f;
      hv.y = qu.y ? (_Float16)1.0f : (_Float16)0.0f;
      hv.z = qu.z ? (_Float16)1.0f : (_Float16)0.0f;
      hv.w = qu.w ? (_Float16)1.0f : (_Float16)0.0f;
      *(half4v*)&Qs[n * 72 + d4] = hv;
    }
    __syncthreads();

    half8v af[2];
#pragma unroll
    for (int kk = 0; kk < 2; ++kk)
      af[kk] = *(const half8v*)&KVT[(wave * 16 + ln15) * 72 + kk * 32 + lq * 8];

#pragma unroll
    for (int nt = 0; nt < 8; ++nt) {
      f32x4 a = (f32x4){0.f, 0.f, 0.f, 0.f};
#pragma unroll
      for (int kk = 0; kk < 2; ++kk) {
        half8v bf = *(const half8v*)&Qs[(nt * 16 + ln15) * 72 + kk * 32 + lq * 8];
        a = __builtin_amdgcn_mfma_f32_16x16x32_f16(af[kk], bf, a, 0, 0, 0);
      }
      unsigned short sj[4];
#pragma unroll
      for (int r = 0; r < 4; ++r) {
        float y = a[r] * 0.125f;
        float v = vm[nt][r] + (y - vm[nt][r]) * 0.5f;
        bool s = (v >= 1.0f);
        sj[r] = s ? 0x3F80 : 0;
        vm[nt][r] = s ? 0.f : v;
      }
      int n = n0 + nt * 16 + ln15;
      int c0 = h * D_ + wave * 16 + lq * 4;
      *(ushort4*)&sa[((size_t)(t * B_ + b) * N_ + n) * C_ + c0] =
          make_ushort4(sj[0], sj[1], sj[2], sj[3]);
    }
  }
}

// ---------------------------------------------------------------------------
// proj GEMM (3-product: W digits x exact bf16 spikes) + connecting LIF.
// grid (4=ot, 32=ntb, 16=b), block 256.
// ---------------------------------------------------------------------------
__global__ __launch_bounds__(256) void proj_mfma(
    const unsigned short* __restrict__ wb, const unsigned short* __restrict__ sa,
    const float* __restrict__ bp, const float* __restrict__ x,
    float* __restrict__ out)
{
  // LDS: WS[3][128][32] (24KB) + SS[4][32][32] (8KB)
  __shared__ __align__(16) char lds[32768];
  const int tid = threadIdx.x;
  const int lane = tid & 63, wave = tid >> 6;
  const int ln15 = lane & 15, lq = lane >> 4;
  const int ot = blockIdx.x, ntb = blockIdx.y, b = blockIdx.z;
  const int o0 = ot * 128, n0 = ntb * 32;

  const unsigned short* gsrc[8];
#pragma unroll
  for (int i = 0; i < 8; ++i) {
    int u = i * 256 + tid;
    if (u < 1536) {
      int s = u >> 9, rem = u & 511;
      int row = rem >> 2, pc = rem & 3;
      int lc = pc ^ ((row >> 1) & 3);
      gsrc[i] = wb + (((size_t)(3 * 3 + s)) << 18) + (size_t)(o0 + row) * C_ + lc * 8;
    } else {
      int v = u - 1536;
      int t = v >> 7, rem2 = v & 127;
      int row = rem2 >> 2, pc = rem2 & 3;
      int lc = pc ^ ((row >> 1) & 3);
      gsrc[i] = sa + ((size_t)((t * B_ + b) * N_ + n0 + row)) * C_ + lc * 8;
    }
  }

  f32x4 acc[T_][2][2];
#pragma unroll
  for (int t = 0; t < T_; ++t)
#pragma unroll
    for (int mt = 0; mt < 2; ++mt)
#pragma unroll
      for (int nt = 0; nt < 2; ++nt)
        acc[t][mt][nt] = (f32x4){0.f, 0.f, 0.f, 0.f};

  int offA[3][2], offB[2];
#pragma unroll
  for (int s = 0; s < 3; ++s)
#pragma unroll
    for (int mt = 0; mt < 2; ++mt) {
      int r = wave * 32 + mt * 16 + ln15;
      offA[s][mt] = s * 8192 + r * 64 + ((lq ^ ((r >> 1) & 3)) << 4);
    }
#pragma unroll
  for (int nt = 0; nt < 2; ++nt) {
    int n = nt * 16 + ln15;
    offB[nt] = 24576 + n * 64 + ((lq ^ ((n >> 1) & 3)) << 4);
  }

  for (int kk = 0; kk < 16; ++kk) {
#pragma unroll
    for (int i = 0; i < 8; ++i)
      GLD16(gsrc[i], i * 4096 + (tid & 192) * 16);
    __syncthreads();

    short8 wa[3][2];
#pragma unroll
    for (int s = 0; s < 3; ++s)
#pragma unroll
      for (int mt = 0; mt < 2; ++mt)
        wa[s][mt] = *(const short8*)&lds[offA[s][mt]];

#pragma unroll
    for (int t = 0; t < T_; ++t) {
      short8 xb[2];
#pragma unroll
      for (int nt = 0; nt < 2; ++nt)
        xb[nt] = *(const short8*)&lds[offB[nt] + t * 2048];
#pragma unroll
      for (int mt = 0; mt < 2; ++mt)
#pragma unroll
        for (int nt = 0; nt < 2; ++nt) {
          f32x4 a = acc[t][mt][nt];
          a = __builtin_amdgcn_mfma_f32_16x16x32_bf16(wa[1][mt], xb[nt], a, 0, 0, 0);
          a = __builtin_amdgcn_mfma_f32_16x16x32_bf16(wa[2][mt], xb[nt], a, 0, 0, 0);
          a = __builtin_amdgcn_mfma_f32_16x16x32_bf16(wa[0][mt], xb[nt], a, 0, 0, 0);
          acc[t][mt][nt] = a;
        }
    }
    __syncthreads();
#pragma unroll
    for (int i = 0; i < 8; ++i) gsrc[i] += 32;
  }

  // epilogue: connecting LIF with identity shortcut
#pragma unroll
  for (int mt = 0; mt < 2; ++mt)
#pragma unroll
    for (int r = 0; r < 4; ++r) {
      int o = o0 + wave * 32 + mt * 16 + lq * 4 + r;
      float bo = bp[o];
#pragma unroll
      for (int nt = 0; nt < 2; ++nt) {
        int n = n0 + nt * 16 + ln15;
        float vmem = 0.f;
#pragma unroll
        for (int t = 0; t < T_; ++t) {
          size_t base = ((size_t)(t * B_ + b) * C_ + o) * N_ + n;
          float xv = x[base];
          float pv = acc[t][mt][nt][r] + bo;
          float v = vmem + ((pv + xv) - vmem) * 0.5f;
          bool s = (v >= 1.0f);
          out[base] = s ? 1.0f : 0.0f;
          vmem = s ? 0.f : v;
        }
      }
    }
}

// ---------------------------------------------------------------------------
extern "C" void kernel_launch(void* const* d_in, const int* in_sizes, int n_in,
                              void* d_out, int out_size, void* d_ws, size_t ws_size,
                              hipStream_t stream)
{
  const float* x  = (const float*)d_in[0];
  const float* Wq = (const float*)d_in[1];
  const float* bq = (const float*)d_in[2];
  const float* Wk = (const float*)d_in[3];
  const float* bk = (const float*)d_in[4];
  const float* Wv = (const float*)d_in[5];
  const float* bv = (const float*)d_in[6];
  const float* Wp = (const float*)d_in[7];
  const float* bp = (const float*)d_in[8];
  (void)in_sizes; (void)n_in; (void)out_size; (void)ws_size;

  unsigned char* ws = (unsigned char*)d_ws;
  unsigned char* sq = ws;                       // [t,b,n,c] transposed
  unsigned char* sk = ws + SPK_ELEMS;
  unsigned char* sv = ws + 2 * SPK_ELEMS;
  float* kvbuf = (float*)(ws + KV_OFF_N);
  unsigned short* wb = (unsigned short*)(ws + WB_OFF_N);
  unsigned short* xs = (unsigned short*)(ws + XS_OFF_N);
  unsigned short* sa = xs;  // alias digit-0 region (xs dead before attn writes)
  float* out = (float*)d_out;

  convert_w<<<4096, 256, 0, stream>>>(Wq, Wk, Wv, Wp, wb);
  convert_x<<<dim3(32, 16, 64), dim3(32, 8), 0, stream>>>(x, xs);
  qkv_mfma<<<dim3(12, 32, 16), 256, 0, stream>>>(wb, xs, bq, bk, bv, ws);
  kv_kernel<<<dim3(8, 16, 4), 256, 0, stream>>>(sk, sv, kvbuf);
  attn_mfma<<<dim3(8, 8, 16), 256, 0, stream>>>(sq, kvbuf, sa);
  proj_mfma<<<dim3(4, 32, 16), 256, 0, stream>>>(wb, sa, bp, x, out);
}

// Round 5
// 1015.773 us; speedup vs baseline: 1.8369x; 1.0505x over previous
//
#include <hip/hip_runtime.h>

// Problem constants
#define T_ 4
#define B_ 16
#define C_ 512
#define N_ 1024
#define H_ 8
#define D_ 64
#define SPK_ELEMS (33554432ull)   // T*B*C*N

typedef short short8 __attribute__((ext_vector_type(8)));
typedef _Float16 half8v __attribute__((ext_vector_type(8)));
typedef _Float16 half4v __attribute__((ext_vector_type(4)));
typedef float f32x4 __attribute__((ext_vector_type(4)));

// ---------------- workspace layout (bytes) ----------------
// sq:  [0, 33554432)            uint8 q spikes  [t,b,n,c]  (TRANSPOSED)
// sk:  [33554432, 67108864)     uint8 k spikes  [t,b,c,n]
// sv:  [67108864, 100663296)    uint8 v spikes  [t,b,c,n]
// kv:  [100663296, 109051904)   fp32  [t,b,h,d,e]
// wb:  [109051904, 115343360)   bf16  [p=4][digit=3][512][512]
// xs:  [115343360, 316669952)   bf16  [digit=3][t][b][n][c]
// sa:  aliases xs digit-0 region (xs dead before attn writes it)
#define KV_OFF_N  100663296ull
#define WB_OFF_N  109051904ull
#define XS_OFF_N  115343360ull

__device__ __forceinline__ unsigned short bf_rne(float f) {
  unsigned u = __float_as_uint(f);
  unsigned r = (u + 0x7FFFu + ((u >> 16) & 1u)) >> 16;
  return (unsigned short)r;
}
__device__ __forceinline__ float bf2f(unsigned short h) {
  return __uint_as_float(((unsigned)h) << 16);
}

#define GLD16(gp, loff) \
  __builtin_amdgcn_global_load_lds( \
      (const __attribute__((address_space(1))) void*)(gp), \
      (__attribute__((address_space(3))) void*)(lds + (loff)), 16, 0, 0)

// ---------------------------------------------------------------------------
// W [4 mats][512][512] fp32 -> wb [p][3][512][512] bf16 digits (RNE cascade)
// ---------------------------------------------------------------------------
__global__ __launch_bounds__(256) void convert_w(
    const float* __restrict__ w0, const float* __restrict__ w1,
    const float* __restrict__ w2, const float* __restrict__ w3,
    unsigned short* __restrict__ wb)
{
  int idx = blockIdx.x * 256 + threadIdx.x;      // 0..1048575
  int p = idx >> 18, rem = idx & 262143;
  const float* src = (p == 0) ? w0 : (p == 1) ? w1 : (p == 2) ? w2 : w3;
  float v = src[rem];
  unsigned short h1 = bf_rne(v);
  float r1 = v - bf2f(h1);
  unsigned short h2 = bf_rne(r1);
  float r2 = r1 - bf2f(h2);
  unsigned short h3 = bf_rne(r2);
  size_t base = ((size_t)(p * 3)) << 18;
  wb[base + rem] = h1;
  wb[base + 262144 + rem] = h2;
  wb[base + 524288 + rem] = h3;
}

// ---------------------------------------------------------------------------
// x [t,b,c,n] fp32 -> xs [digit=3][t,b,n,c] bf16 (transposed inner dims)
// ---------------------------------------------------------------------------
__global__ __launch_bounds__(256) void convert_x(
    const float* __restrict__ x, unsigned short* __restrict__ xs)
{
  __shared__ float tile[32][33];
  const int tb = blockIdx.z;
  const int c0 = blockIdx.y * 32, n0 = blockIdx.x * 32;
  const int tx = threadIdx.x, ty = threadIdx.y;
  const float* src = x + ((size_t)tb * C_ + c0) * N_ + n0;
#pragma unroll
  for (int k = 0; k < 4; ++k)
    tile[ty + 8 * k][tx] = src[(size_t)(ty + 8 * k) * N_ + tx];
  __syncthreads();
#pragma unroll
  for (int k = 0; k < 4; ++k) {
    int r = ty + 8 * k;                       // n-offset within tile
    float v = tile[tx][r];                    // element (c=c0+tx, n=n0+r)
    unsigned short h1 = bf_rne(v);
    float r1 = v - bf2f(h1);
    unsigned short h2 = bf_rne(r1);
    float r2 = r1 - bf2f(h2);
    unsigned short h3 = bf_rne(r2);
    size_t o = ((size_t)tb * N_ + n0 + r) * C_ + c0 + tx;
    xs[o] = h1;
    xs[o + 33554432ull] = h2;
    xs[o + 67108864ull] = h3;
  }
}

// ---------------------------------------------------------------------------
// Fused q/k/v GEMM (6-product bf16 digit MFMA, single fp32 accumulator) + LIF.
// Block tile 128o x 32n x 4t.  grid (12=(ot|p), 32=ntb, 16=b).
// q spikes written TRANSPOSED [t,b,n,c]; k,v spikes [t,b,c,n].
// ---------------------------------------------------------------------------
__global__ __launch_bounds__(256) void qkv_mfma(
    const unsigned short* __restrict__ wb, const unsigned short* __restrict__ xs,
    const float* __restrict__ bq, const float* __restrict__ bk,
    const float* __restrict__ bv, unsigned char* __restrict__ spikes_base)
{
  // LDS: WS[3][128][32] bf16 (24KB) + XS[3][4][32][32] bf16 (24KB)
  __shared__ __align__(16) char lds[49152];
  const int tid = threadIdx.x;
  const int lane = tid & 63, wave = tid >> 6;
  const int ln15 = lane & 15, lq = lane >> 4;
  const int ot = blockIdx.x & 3, p = blockIdx.x >> 2;
  const int ntb = blockIdx.y, b = blockIdx.z;
  const int o0 = ot * 128, n0 = ntb * 32;

  // staging sources: 12 x 16B per thread per k-iter (48KB total)
  const unsigned short* gsrc[12];
#pragma unroll
  for (int i = 0; i < 12; ++i) {
    int u = i * 256 + tid;
    if (u < 1536) {               // W region
      int s = u >> 9, rem = u & 511;
      int row = rem >> 2, pc = rem & 3;
      int lc = pc ^ ((row >> 1) & 3);
      gsrc[i] = wb + (((size_t)(p * 3 + s)) << 18) + (size_t)(o0 + row) * C_ + lc * 8;
    } else {                      // X region
      int v = u - 1536;
      int s = v >> 9, rem = v & 511;
      int t = rem >> 7, rem2 = rem & 127;
      int row = rem2 >> 2, pc = rem2 & 3;
      int lc = pc ^ ((row >> 1) & 3);
      gsrc[i] = xs + ((size_t)s * 33554432ull) +
                ((size_t)((t * B_ + b) * N_ + n0 + row)) * C_ + lc * 8;
    }
  }

  f32x4 acc[T_][2][2];
#pragma unroll
  for (int t = 0; t < T_; ++t)
#pragma unroll
    for (int mt = 0; mt < 2; ++mt)
#pragma unroll
      for (int nt = 0; nt < 2; ++nt)
        acc[t][mt][nt] = (f32x4){0.f, 0.f, 0.f, 0.f};

  int offA[3][2], offB[3][2];
#pragma unroll
  for (int s = 0; s < 3; ++s) {
#pragma unroll
    for (int mt = 0; mt < 2; ++mt) {
      int r = wave * 32 + mt * 16 + ln15;
      offA[s][mt] = s * 8192 + r * 64 + ((lq ^ ((r >> 1) & 3)) << 4);
    }
#pragma unroll
    for (int nt = 0; nt < 2; ++nt) {
      int n = nt * 16 + ln15;
      offB[s][nt] = 24576 + s * 8192 + n * 64 + ((lq ^ ((n >> 1) & 3)) << 4);
    }
  }

  for (int kk = 0; kk < 16; ++kk) {
#pragma unroll
    for (int i = 0; i < 12; ++i)
      GLD16(gsrc[i], i * 4096 + (tid & 192) * 16);
    __syncthreads();

    short8 wa[3][2];
#pragma unroll
    for (int s = 0; s < 3; ++s)
#pragma unroll
      for (int mt = 0; mt < 2; ++mt)
        wa[s][mt] = *(const short8*)&lds[offA[s][mt]];

#pragma unroll
    for (int t = 0; t < T_; ++t) {
      short8 xb[3][2];
#pragma unroll
      for (int s = 0; s < 3; ++s)
#pragma unroll
        for (int nt = 0; nt < 2; ++nt)
          xb[s][nt] = *(const short8*)&lds[offB[s][nt] + t * 2048];
#pragma unroll
      for (int mt = 0; mt < 2; ++mt)
#pragma unroll
        for (int nt = 0; nt < 2; ++nt) {
          f32x4 a = acc[t][mt][nt];
          a = __builtin_amdgcn_mfma_f32_16x16x32_bf16(wa[0][mt], xb[1][nt], a, 0, 0, 0);
          a = __builtin_amdgcn_mfma_f32_16x16x32_bf16(wa[1][mt], xb[0][nt], a, 0, 0, 0);
          a = __builtin_amdgcn_mfma_f32_16x16x32_bf16(wa[0][mt], xb[2][nt], a, 0, 0, 0);
          a = __builtin_amdgcn_mfma_f32_16x16x32_bf16(wa[2][mt], xb[0][nt], a, 0, 0, 0);
          a = __builtin_amdgcn_mfma_f32_16x16x32_bf16(wa[1][mt], xb[1][nt], a, 0, 0, 0);
          a = __builtin_amdgcn_mfma_f32_16x16x32_bf16(wa[0][mt], xb[0][nt], a, 0, 0, 0);
          acc[t][mt][nt] = a;
        }
    }
    __syncthreads();
#pragma unroll
    for (int i = 0; i < 12; ++i) gsrc[i] += 32;
  }

  // epilogue: bias + LIF over t
  const float* bias = (p == 0) ? bq : (p == 1) ? bk : bv;
  if (p == 0) {
    // q: transposed store [t,b,n,c], contiguous uchar4 along c
    unsigned char* spq = spikes_base;
#pragma unroll
    for (int mt = 0; mt < 2; ++mt) {
      int obase = o0 + wave * 32 + mt * 16 + lq * 4;
      float b4[4] = {bias[obase], bias[obase + 1], bias[obase + 2], bias[obase + 3]};
#pragma unroll
      for (int nt = 0; nt < 2; ++nt) {
        int n = n0 + nt * 16 + ln15;
        float vm[4] = {0.f, 0.f, 0.f, 0.f};
#pragma unroll
        for (int t = 0; t < T_; ++t) {
          unsigned char sj[4];
#pragma unroll
          for (int r = 0; r < 4; ++r) {
            float y = acc[t][mt][nt][r] + b4[r];
            float v = vm[r] + (y - vm[r]) * 0.5f;
            bool s = (v >= 1.0f);
            sj[r] = s ? 1 : 0;
            vm[r] = s ? 0.f : v;
          }
          *(uchar4*)&spq[((size_t)(t * B_ + b) * N_ + n) * C_ + obase] =
              make_uchar4(sj[0], sj[1], sj[2], sj[3]);
        }
      }
    }
  } else {
    unsigned char* sp = spikes_base + (size_t)p * SPK_ELEMS;
#pragma unroll
    for (int mt = 0; mt < 2; ++mt)
#pragma unroll
      for (int r = 0; r < 4; ++r) {
        int o = o0 + wave * 32 + mt * 16 + lq * 4 + r;
        float bo = bias[o];
#pragma unroll
        for (int nt = 0; nt < 2; ++nt) {
          int n = n0 + nt * 16 + ln15;
          float vmem = 0.f;
#pragma unroll
          for (int t = 0; t < T_; ++t) {
            float y = acc[t][mt][nt][r] + bo;
            float v = vmem + (y - vmem) * 0.5f;
            bool s = (v >= 1.0f);
            sp[((size_t)(t * B_ + b) * C_ + o) * N_ + n] = s ? 1 : 0;
            vmem = s ? 0.f : v;
          }
        }
      }
  }
}

// ---------------------------------------------------------------------------
// kv[t,b,h,d,e] = sum_n k[d,n]*v[e,n] via f16 MFMA (binary inputs, ints
// <=1024 in fp32 acc: bit-exact). grid (H,B,T), block 256 (wave = d-tile).
// ---------------------------------------------------------------------------
__global__ __launch_bounds__(256) void kv_f16(
    const unsigned char* __restrict__ sk, const unsigned char* __restrict__ sv,
    float* __restrict__ kvout)
{
  __shared__ _Float16 Kf[64 * 264];   // [d][n-chunk 256], pitch 264
  __shared__ _Float16 Vf[64 * 264];   // [e][n-chunk 256]
  const int tid = threadIdx.x;
  const int lane = tid & 63, wave = tid >> 6;
  const int ln15 = lane & 15, lq = lane >> 4;
  const int h = blockIdx.x, b = blockIdx.y, t = blockIdx.z;

  const unsigned char* kb = sk + ((size_t)(t * B_ + b) * C_ + h * D_) * N_;
  const unsigned char* vb = sv + ((size_t)(t * B_ + b) * C_ + h * D_) * N_;

  f32x4 acc[4];
#pragma unroll
  for (int et = 0; et < 4; ++et) acc[et] = (f32x4){0.f, 0.f, 0.f, 0.f};

  const int row = tid >> 2, seg = (tid & 3) * 64;   // 64B of one row per thread

  for (int nc = 0; nc < N_; nc += 256) {
    const unsigned char* kr = kb + (size_t)row * N_ + nc + seg;
    const unsigned char* vr = vb + (size_t)row * N_ + nc + seg;
#pragma unroll
    for (int j = 0; j < 16; ++j) {
      // u8 {0,1} -> f16 bits via packed multiply by 0x3C00
      unsigned wk = *(const unsigned*)(kr + j * 4);
      unsigned lo = ((wk & 0xFFu) | ((wk & 0xFF00u) << 8)) * 0x3C00u;
      unsigned hi = (((wk >> 16) & 0xFFu) | ((wk >> 8) & 0xFF0000u)) * 0x3C00u;
      *(uint2*)&Kf[row * 264 + seg + j * 4] = make_uint2(lo, hi);
      unsigned wv = *(const unsigned*)(vr + j * 4);
      unsigned lo2 = ((wv & 0xFFu) | ((wv & 0xFF00u) << 8)) * 0x3C00u;
      unsigned hi2 = (((wv >> 16) & 0xFFu) | ((wv >> 8) & 0xFF0000u)) * 0x3C00u;
      *(uint2*)&Vf[row * 264 + seg + j * 4] = make_uint2(lo2, hi2);
    }
    __syncthreads();
#pragma unroll
    for (int ks = 0; ks < 8; ++ks) {
      half8v a = *(const half8v*)&Kf[(wave * 16 + ln15) * 264 + ks * 32 + lq * 8];
#pragma unroll
      for (int et = 0; et < 4; ++et) {
        half8v bf = *(const half8v*)&Vf[(et * 16 + ln15) * 264 + ks * 32 + lq * 8];
        acc[et] = __builtin_amdgcn_mfma_f32_16x16x32_f16(a, bf, acc[et], 0, 0, 0);
      }
    }
    __syncthreads();
  }

  float* o = kvout + ((size_t)(t * B_ + b) * H_ + h) * (D_ * D_);
#pragma unroll
  for (int et = 0; et < 4; ++et)
#pragma unroll
    for (int r = 0; r < 4; ++r) {
      int d = wave * 16 + lq * 4 + r;
      int e = et * 16 + ln15;
      o[d * D_ + e] = acc[et][r];
    }
}

// ---------------------------------------------------------------------------
// attn: out[e][n] = sum_d kvT[e][d] * q[n][d], *0.125, LIF over t.
// f16 MFMA — q in {0,1}, kv ints <=1024: exact. Writes sa bf16 [t,b,n,c].
// grid (8 n-tiles of 128, H, B), block 256 (wave w = e-tile).
// ---------------------------------------------------------------------------
__global__ __launch_bounds__(256) void attn_mfma(
    const unsigned char* __restrict__ sq2, const float* __restrict__ kv,
    unsigned short* __restrict__ sa)
{
  __shared__ _Float16 Qs[128 * 72];    // [n][d] pitch 72
  __shared__ _Float16 KVT[64 * 72];    // [e][d] pitch 72
  const int tid = threadIdx.x;
  const int lane = tid & 63, wave = tid >> 6;   // wave = e-tile
  const int ln15 = lane & 15, lq = lane >> 4;
  const int n0 = blockIdx.x * 128;
  const int h = blockIdx.y, b = blockIdx.z;

  f32x4 vm[8];
#pragma unroll
  for (int nt = 0; nt < 8; ++nt) vm[nt] = (f32x4){0.f, 0.f, 0.f, 0.f};

  for (int t = 0; t < T_; ++t) {
    __syncthreads();
    const float* kvb = kv + ((size_t)(t * B_ + b) * H_ + h) * (D_ * D_);
#pragma unroll
    for (int l = 0; l < 16; ++l) {
      int idx = l * 256 + tid;
      int e = idx & 63, d = idx >> 6;
      KVT[e * 72 + d] = (_Float16)kvb[d * 64 + e];   // ints <=1024: exact
    }
    const unsigned char* qb = sq2 + ((size_t)(t * B_ + b) * N_ + n0) * C_ + h * D_;
#pragma unroll
    for (int l = 0; l < 8; ++l) {
      int idx = l * 256 + tid;
      int n = idx >> 4, d4 = (idx & 15) * 4;
      uchar4 qu = *(const uchar4*)&qb[(size_t)n * C_ + d4];
      half4v hv;
      hv.x = qu.x ? (_Float16)1.0f : (_Float16)0.0f;
      hv.y = qu.y ? (_Float16)1.0f : (_Float16)0.0f;
      hv.z = qu.z ? (_Float16)1.0f : (_Float16)0.0f;
      hv.w = qu.w ? (_Float16)1.0f : (_Float16)0.0f;
      *(half4v*)&Qs[n * 72 + d4] = hv;
    }
    __syncthreads();

    half8v af[2];
#pragma unroll
    for (int kk = 0; kk < 2; ++kk)
      af[kk] = *(const half8v*)&KVT[(wave * 16 + ln15) * 72 + kk * 32 + lq * 8];

#pragma unroll
    for (int nt = 0; nt < 8; ++nt) {
      f32x4 a = (f32x4){0.f, 0.f, 0.f, 0.f};
#pragma unroll
      for (int kk = 0; kk < 2; ++kk) {
        half8v bf = *(const half8v*)&Qs[(nt * 16 + ln15) * 72 + kk * 32 + lq * 8];
        a = __builtin_amdgcn_mfma_f32_16x16x32_f16(af[kk], bf, a, 0, 0, 0);
      }
      unsigned short sj[4];
#pragma unroll
      for (int r = 0; r < 4; ++r) {
        float y = a[r] * 0.125f;
        float v = vm[nt][r] + (y - vm[nt][r]) * 0.5f;
        bool s = (v >= 1.0f);
        sj[r] = s ? 0x3F80 : 0;
        vm[nt][r] = s ? 0.f : v;
      }
      int n = n0 + nt * 16 + ln15;
      int c0 = h * D_ + wave * 16 + lq * 4;
      *(ushort4*)&sa[((size_t)(t * B_ + b) * N_ + n) * C_ + c0] =
          make_ushort4(sj[0], sj[1], sj[2], sj[3]);
    }
  }
}

// ---------------------------------------------------------------------------
// proj GEMM (3-product exact: W digits x exact bf16 spikes) + connecting LIF.
// grid (4=ot, 32=ntb, 16=b), block 256.
// ---------------------------------------------------------------------------
__global__ __launch_bounds__(256) void proj_mfma(
    const unsigned short* __restrict__ wb, const unsigned short* __restrict__ sa,
    const float* __restrict__ bp, const float* __restrict__ x,
    float* __restrict__ out)
{
  // LDS: WS[3][128][32] (24KB) + SS[4][32][32] (8KB)
  __shared__ __align__(16) char lds[32768];
  const int tid = threadIdx.x;
  const int lane = tid & 63, wave = tid >> 6;
  const int ln15 = lane & 15, lq = lane >> 4;
  const int ot = blockIdx.x, ntb = blockIdx.y, b = blockIdx.z;
  const int o0 = ot * 128, n0 = ntb * 32;

  const unsigned short* gsrc[8];
#pragma unroll
  for (int i = 0; i < 8; ++i) {
    int u = i * 256 + tid;
    if (u < 1536) {
      int s = u >> 9, rem = u & 511;
      int row = rem >> 2, pc = rem & 3;
      int lc = pc ^ ((row >> 1) & 3);
      gsrc[i] = wb + (((size_t)(3 * 3 + s)) << 18) + (size_t)(o0 + row) * C_ + lc * 8;
    } else {
      int v = u - 1536;
      int t = v >> 7, rem2 = v & 127;
      int row = rem2 >> 2, pc = rem2 & 3;
      int lc = pc ^ ((row >> 1) & 3);
      gsrc[i] = sa + ((size_t)((t * B_ + b) * N_ + n0 + row)) * C_ + lc * 8;
    }
  }

  f32x4 acc[T_][2][2];
#pragma unroll
  for (int t = 0; t < T_; ++t)
#pragma unroll
    for (int mt = 0; mt < 2; ++mt)
#pragma unroll
      for (int nt = 0; nt < 2; ++nt)
        acc[t][mt][nt] = (f32x4){0.f, 0.f, 0.f, 0.f};

  int offA[3][2], offB[2];
#pragma unroll
  for (int s = 0; s < 3; ++s)
#pragma unroll
    for (int mt = 0; mt < 2; ++mt) {
      int r = wave * 32 + mt * 16 + ln15;
      offA[s][mt] = s * 8192 + r * 64 + ((lq ^ ((r >> 1) & 3)) << 4);
    }
#pragma unroll
  for (int nt = 0; nt < 2; ++nt) {
    int n = nt * 16 + ln15;
    offB[nt] = 24576 + n * 64 + ((lq ^ ((n >> 1) & 3)) << 4);
  }

  for (int kk = 0; kk < 16; ++kk) {
#pragma unroll
    for (int i = 0; i < 8; ++i)
      GLD16(gsrc[i], i * 4096 + (tid & 192) * 16);
    __syncthreads();

    short8 wa[3][2];
#pragma unroll
    for (int s = 0; s < 3; ++s)
#pragma unroll
      for (int mt = 0; mt < 2; ++mt)
        wa[s][mt] = *(const short8*)&lds[offA[s][mt]];

#pragma unroll
    for (int t = 0; t < T_; ++t) {
      short8 xb[2];
#pragma unroll
      for (int nt = 0; nt < 2; ++nt)
        xb[nt] = *(const short8*)&lds[offB[nt] + t * 2048];
#pragma unroll
      for (int mt = 0; mt < 2; ++mt)
#pragma unroll
        for (int nt = 0; nt < 2; ++nt) {
          f32x4 a = acc[t][mt][nt];
          a = __builtin_amdgcn_mfma_f32_16x16x32_bf16(wa[1][mt], xb[nt], a, 0, 0, 0);
          a = __builtin_amdgcn_mfma_f32_16x16x32_bf16(wa[2][mt], xb[nt], a, 0, 0, 0);
          a = __builtin_amdgcn_mfma_f32_16x16x32_bf16(wa[0][mt], xb[nt], a, 0, 0, 0);
          acc[t][mt][nt] = a;
        }
    }
    __syncthreads();
#pragma unroll
    for (int i = 0; i < 8; ++i) gsrc[i] += 32;
  }

  // epilogue: connecting LIF with identity shortcut
#pragma unroll
  for (int mt = 0; mt < 2; ++mt)
#pragma unroll
    for (int r = 0; r < 4; ++r) {
      int o = o0 + wave * 32 + mt * 16 + lq * 4 + r;
      float bo = bp[o];
#pragma unroll
      for (int nt = 0; nt < 2; ++nt) {
        int n = n0 + nt * 16 + ln15;
        float vmem = 0.f;
#pragma unroll
        for (int t = 0; t < T_; ++t) {
          size_t base = ((size_t)(t * B_ + b) * C_ + o) * N_ + n;
          float xv = x[base];
          float pv = acc[t][mt][nt][r] + bo;
          float v = vmem + ((pv + xv) - vmem) * 0.5f;
          bool s = (v >= 1.0f);
          out[base] = s ? 1.0f : 0.0f;
          vmem = s ? 0.f : v;
        }
      }
    }
}

// ---------------------------------------------------------------------------
extern "C" void kernel_launch(void* const* d_in, const int* in_sizes, int n_in,
                              void* d_out, int out_size, void* d_ws, size_t ws_size,
                              hipStream_t stream)
{
  const float* x  = (const float*)d_in[0];
  const float* Wq = (const float*)d_in[1];
  const float* bq = (const float*)d_in[2];
  const float* Wk = (const float*)d_in[3];
  const float* bk = (const float*)d_in[4];
  const float* Wv = (const float*)d_in[5];
  const float* bv = (const float*)d_in[6];
  const float* Wp = (const float*)d_in[7];
  const float* bp = (const float*)d_in[8];
  (void)in_sizes; (void)n_in; (void)out_size; (void)ws_size;

  unsigned char* ws = (unsigned char*)d_ws;
  unsigned char* sq = ws;                       // [t,b,n,c] transposed
  unsigned char* sk = ws + SPK_ELEMS;
  unsigned char* sv = ws + 2 * SPK_ELEMS;
  float* kvbuf = (float*)(ws + KV_OFF_N);
  unsigned short* wb = (unsigned short*)(ws + WB_OFF_N);
  unsigned short* xs = (unsigned short*)(ws + XS_OFF_N);
  unsigned short* sa = xs;  // alias digit-0 region (xs dead before attn writes)
  float* out = (float*)d_out;

  convert_w<<<4096, 256, 0, stream>>>(Wq, Wk, Wv, Wp, wb);
  convert_x<<<dim3(32, 16, 64), dim3(32, 8), 0, stream>>>(x, xs);
  qkv_mfma<<<dim3(12, 32, 16), 256, 0, stream>>>(wb, xs, bq, bk, bv, ws);
  kv_f16<<<dim3(8, 16, 4), 256, 0, stream>>>(sk, sv, kvbuf);
  attn_mfma<<<dim3(8, 8, 16), 256, 0, stream>>>(sq, kvbuf, sa);
  proj_mfma<<<dim3(4, 32, 16), 256, 0, stream>>>(wb, sa, bp, x, out);
}

// Round 6
// 809.804 us; speedup vs baseline: 2.3041x; 1.2543x over previous
//
#include <hip/hip_runtime.h>

// Problem constants
#define T_ 4
#define B_ 16
#define C_ 512
#define N_ 1024
#define H_ 8
#define D_ 64
#define SPK_ELEMS (33554432ull)   // T*B*C*N

typedef _Float16 half8v __attribute__((ext_vector_type(8)));
typedef _Float16 half4v __attribute__((ext_vector_type(4)));
typedef float f32x4 __attribute__((ext_vector_type(4)));

// ---------------- workspace layout (bytes) ----------------
// sq:  [0, 33554432)            uint8 q spikes  [t,b,n,c]  (TRANSPOSED)
// sk:  [33554432, 67108864)     uint8 k spikes  [t,b,c,n]
// sv:  [67108864, 100663296)    uint8 v spikes  [t,b,c,n]
// kv:  [100663296, 109051904)   fp32  [t,b,h,d,e]
// wb:  [109051904, 113246208)   f16   [p=4][digit=2][512][512], W pre-scaled by 2^12
// xs:  [113246208, 247463936)   f16   [digit=2][t][b][n][c],    x pre-scaled by 2^11
// sa:  aliases xs digit-0 region (xs dead before attn writes it); f16 {0,1}
#define KV_OFF_N  100663296ull
#define WB_OFF_N  109051904ull
#define XS_OFF_N  113246208ull

#define QKV_INV_SCALE (1.0f / 8388608.0f)   // 2^-23  (Sx=2^11 * Sw=2^12)
#define PROJ_INV_SCALE (1.0f / 4096.0f)     // 2^-12  (Sw only; spikes unscaled)

#define GLD16(gp, loff) \
  __builtin_amdgcn_global_load_lds( \
      (const __attribute__((address_space(1))) void*)(gp), \
      (__attribute__((address_space(3))) void*)(lds + (loff)), 16, 0, 0)

// ---------------------------------------------------------------------------
// W [4 mats][512][512] fp32 -> wb [p][2][512][512] f16 digits of W*2^12.
// Exact split: h1 = RNE_f16(v), h2 = RNE_f16(v - h1); v - h1 exact (Sterbenz).
// ---------------------------------------------------------------------------
__global__ __launch_bounds__(256) void convert_w(
    const float* __restrict__ w0, const float* __restrict__ w1,
    const float* __restrict__ w2, const float* __restrict__ w3,
    _Float16* __restrict__ wb)
{
  int idx = blockIdx.x * 256 + threadIdx.x;      // 0..1048575
  int p = idx >> 18, rem = idx & 262143;
  const float* src = (p == 0) ? w0 : (p == 1) ? w1 : (p == 2) ? w2 : w3;
  float v = src[rem] * 4096.0f;                  // exact pow2 scale
  _Float16 h1 = (_Float16)v;
  float r1 = v - (float)h1;
  _Float16 h2 = (_Float16)r1;
  size_t base = ((size_t)(p * 2)) << 18;
  wb[base + rem] = h1;
  wb[base + 262144 + rem] = h2;
}

// ---------------------------------------------------------------------------
// x [t,b,c,n] fp32 -> xs [digit=2][t,b,n,c] f16 digits of x*2^11 (transposed)
// ---------------------------------------------------------------------------
__global__ __launch_bounds__(256) void convert_x(
    const float* __restrict__ x, _Float16* __restrict__ xs)
{
  __shared__ float tile[32][33];
  const int tb = blockIdx.z;
  const int c0 = blockIdx.y * 32, n0 = blockIdx.x * 32;
  const int tx = threadIdx.x, ty = threadIdx.y;
  const float* src = x + ((size_t)tb * C_ + c0) * N_ + n0;
#pragma unroll
  for (int k = 0; k < 4; ++k)
    tile[ty + 8 * k][tx] = src[(size_t)(ty + 8 * k) * N_ + tx];
  __syncthreads();
#pragma unroll
  for (int k = 0; k < 4; ++k) {
    int r = ty + 8 * k;                       // n-offset within tile
    float v = tile[tx][r] * 2048.0f;          // exact pow2 scale
    _Float16 h1 = (_Float16)v;
    float r1 = v - (float)h1;
    _Float16 h2 = (_Float16)r1;
    size_t o = ((size_t)tb * N_ + n0 + r) * C_ + c0 + tx;
    xs[o] = h1;
    xs[o + 33554432ull] = h2;
  }
}

// ---------------------------------------------------------------------------
// Fused q/k/v GEMM (3-product f16 2x2-digit MFMA, fp32 acc) + LIF.
// Block tile 128o x 32n x 4t.  grid (12=(ot|p), 32=ntb, 16=b).
// y = acc * 2^-23 + bias. q spikes TRANSPOSED [t,b,n,c]; k,v [t,b,c,n].
// ---------------------------------------------------------------------------
__global__ __launch_bounds__(256) void qkv_mfma(
    const _Float16* __restrict__ wb, const _Float16* __restrict__ xs,
    const float* __restrict__ bq, const float* __restrict__ bk,
    const float* __restrict__ bv, unsigned char* __restrict__ spikes_base)
{
  // LDS: WS[2][128][32] f16 (16KB) + XS[2][4][32][32] f16 (16KB)
  __shared__ __align__(16) char lds[32768];
  const int tid = threadIdx.x;
  const int lane = tid & 63, wave = tid >> 6;
  const int ln15 = lane & 15, lq = lane >> 4;
  const int ot = blockIdx.x & 3, p = blockIdx.x >> 2;
  const int ntb = blockIdx.y, b = blockIdx.z;
  const int o0 = ot * 128, n0 = ntb * 32;

  // staging sources: 8 x 16B per thread per k-iter (32KB total)
  const _Float16* gsrc[8];
#pragma unroll
  for (int i = 0; i < 8; ++i) {
    int u = i * 256 + tid;
    if (u < 1024) {               // W region: 2 digits x 128 rows x 4 chunks
      int s = u >> 9, rem = u & 511;
      int row = rem >> 2, pc = rem & 3;
      int lc = pc ^ ((row >> 1) & 3);
      gsrc[i] = wb + (((size_t)(p * 2 + s)) << 18) + (size_t)(o0 + row) * C_ + lc * 8;
    } else {                      // X region: 2 digits x 4t x 32 rows x 4 chunks
      int v = u - 1024;
      int s = v >> 9, rem = v & 511;
      int t = rem >> 7, rem2 = rem & 127;
      int row = rem2 >> 2, pc = rem2 & 3;
      int lc = pc ^ ((row >> 1) & 3);
      gsrc[i] = xs + ((size_t)s * 33554432ull) +
                ((size_t)((t * B_ + b) * N_ + n0 + row)) * C_ + lc * 8;
    }
  }

  f32x4 acc[T_][2][2];
#pragma unroll
  for (int t = 0; t < T_; ++t)
#pragma unroll
    for (int mt = 0; mt < 2; ++mt)
#pragma unroll
      for (int nt = 0; nt < 2; ++nt)
        acc[t][mt][nt] = (f32x4){0.f, 0.f, 0.f, 0.f};

  int offA[2][2], offB[2][2];
#pragma unroll
  for (int s = 0; s < 2; ++s) {
#pragma unroll
    for (int mt = 0; mt < 2; ++mt) {
      int r = wave * 32 + mt * 16 + ln15;
      offA[s][mt] = s * 8192 + r * 64 + ((lq ^ ((r >> 1) & 3)) << 4);
    }
#pragma unroll
    for (int nt = 0; nt < 2; ++nt) {
      int n = nt * 16 + ln15;
      offB[s][nt] = 16384 + s * 8192 + n * 64 + ((lq ^ ((n >> 1) & 3)) << 4);
    }
  }

  for (int kk = 0; kk < 16; ++kk) {
#pragma unroll
    for (int i = 0; i < 8; ++i)
      GLD16(gsrc[i], i * 4096 + (tid & 192) * 16);
    __syncthreads();

    half8v wa[2][2];
#pragma unroll
    for (int s = 0; s < 2; ++s)
#pragma unroll
      for (int mt = 0; mt < 2; ++mt)
        wa[s][mt] = *(const half8v*)&lds[offA[s][mt]];

#pragma unroll
    for (int t = 0; t < T_; ++t) {
      half8v xb[2][2];
#pragma unroll
      for (int s = 0; s < 2; ++s)
#pragma unroll
        for (int nt = 0; nt < 2; ++nt)
          xb[s][nt] = *(const half8v*)&lds[offB[s][nt] + t * 2048];
#pragma unroll
      for (int mt = 0; mt < 2; ++mt)
#pragma unroll
        for (int nt = 0; nt < 2; ++nt) {
          f32x4 a = acc[t][mt][nt];
          a = __builtin_amdgcn_mfma_f32_16x16x32_f16(wa[0][mt], xb[1][nt], a, 0, 0, 0);
          a = __builtin_amdgcn_mfma_f32_16x16x32_f16(wa[1][mt], xb[0][nt], a, 0, 0, 0);
          a = __builtin_amdgcn_mfma_f32_16x16x32_f16(wa[0][mt], xb[0][nt], a, 0, 0, 0);
          acc[t][mt][nt] = a;
        }
    }
    __syncthreads();
#pragma unroll
    for (int i = 0; i < 8; ++i) gsrc[i] += 32;
  }

  // epilogue: unscale + bias + LIF over t
  const float* bias = (p == 0) ? bq : (p == 1) ? bk : bv;
  if (p == 0) {
    unsigned char* spq = spikes_base;
#pragma unroll
    for (int mt = 0; mt < 2; ++mt) {
      int obase = o0 + wave * 32 + mt * 16 + lq * 4;
      float b4[4] = {bias[obase], bias[obase + 1], bias[obase + 2], bias[obase + 3]};
#pragma unroll
      for (int nt = 0; nt < 2; ++nt) {
        int n = n0 + nt * 16 + ln15;
        float vm[4] = {0.f, 0.f, 0.f, 0.f};
#pragma unroll
        for (int t = 0; t < T_; ++t) {
          unsigned char sj[4];
#pragma unroll
          for (int r = 0; r < 4; ++r) {
            float y = acc[t][mt][nt][r] * QKV_INV_SCALE + b4[r];
            float v = vm[r] + (y - vm[r]) * 0.5f;
            bool s = (v >= 1.0f);
            sj[r] = s ? 1 : 0;
            vm[r] = s ? 0.f : v;
          }
          *(uchar4*)&spq[((size_t)(t * B_ + b) * N_ + n) * C_ + obase] =
              make_uchar4(sj[0], sj[1], sj[2], sj[3]);
        }
      }
    }
  } else {
    unsigned char* sp = spikes_base + (size_t)p * SPK_ELEMS;
#pragma unroll
    for (int mt = 0; mt < 2; ++mt)
#pragma unroll
      for (int r = 0; r < 4; ++r) {
        int o = o0 + wave * 32 + mt * 16 + lq * 4 + r;
        float bo = bias[o];
#pragma unroll
        for (int nt = 0; nt < 2; ++nt) {
          int n = n0 + nt * 16 + ln15;
          float vmem = 0.f;
#pragma unroll
          for (int t = 0; t < T_; ++t) {
            float y = acc[t][mt][nt][r] * QKV_INV_SCALE + bo;
            float v = vmem + (y - vmem) * 0.5f;
            bool s = (v >= 1.0f);
            sp[((size_t)(t * B_ + b) * C_ + o) * N_ + n] = s ? 1 : 0;
            vmem = s ? 0.f : v;
          }
        }
      }
  }
}

// ---------------------------------------------------------------------------
// kv[t,b,h,d,e] = sum_n k[d,n]*v[e,n] via f16 MFMA (binary inputs, ints
// <=1024 in fp32 acc: bit-exact). grid (H,B,T), block 256 (wave = d-tile).
// ---------------------------------------------------------------------------
__global__ __launch_bounds__(256) void kv_f16(
    const unsigned char* __restrict__ sk, const unsigned char* __restrict__ sv,
    float* __restrict__ kvout)
{
  __shared__ _Float16 Kf[64 * 264];   // [d][n-chunk 256], pitch 264
  __shared__ _Float16 Vf[64 * 264];   // [e][n-chunk 256]
  const int tid = threadIdx.x;
  const int lane = tid & 63, wave = tid >> 6;
  const int ln15 = lane & 15, lq = lane >> 4;
  const int h = blockIdx.x, b = blockIdx.y, t = blockIdx.z;

  const unsigned char* kb = sk + ((size_t)(t * B_ + b) * C_ + h * D_) * N_;
  const unsigned char* vb = sv + ((size_t)(t * B_ + b) * C_ + h * D_) * N_;

  f32x4 acc[4];
#pragma unroll
  for (int et = 0; et < 4; ++et) acc[et] = (f32x4){0.f, 0.f, 0.f, 0.f};

  const int row = tid >> 2, seg = (tid & 3) * 64;   // 64B of one row per thread

  for (int nc = 0; nc < N_; nc += 256) {
    const unsigned char* kr = kb + (size_t)row * N_ + nc + seg;
    const unsigned char* vr = vb + (size_t)row * N_ + nc + seg;
#pragma unroll
    for (int j = 0; j < 16; ++j) {
      unsigned wk = *(const unsigned*)(kr + j * 4);
      unsigned lo = ((wk & 0xFFu) | ((wk & 0xFF00u) << 8)) * 0x3C00u;
      unsigned hi = (((wk >> 16) & 0xFFu) | ((wk >> 8) & 0xFF0000u)) * 0x3C00u;
      *(uint2*)&Kf[row * 264 + seg + j * 4] = make_uint2(lo, hi);
      unsigned wv = *(const unsigned*)(vr + j * 4);
      unsigned lo2 = ((wv & 0xFFu) | ((wv & 0xFF00u) << 8)) * 0x3C00u;
      unsigned hi2 = (((wv >> 16) & 0xFFu) | ((wv >> 8) & 0xFF0000u)) * 0x3C00u;
      *(uint2*)&Vf[row * 264 + seg + j * 4] = make_uint2(lo2, hi2);
    }
    __syncthreads();
#pragma unroll
    for (int ks = 0; ks < 8; ++ks) {
      half8v a = *(const half8v*)&Kf[(wave * 16 + ln15) * 264 + ks * 32 + lq * 8];
#pragma unroll
      for (int et = 0; et < 4; ++et) {
        half8v bf = *(const half8v*)&Vf[(et * 16 + ln15) * 264 + ks * 32 + lq * 8];
        acc[et] = __builtin_amdgcn_mfma_f32_16x16x32_f16(a, bf, acc[et], 0, 0, 0);
      }
    }
    __syncthreads();
  }

  float* o = kvout + ((size_t)(t * B_ + b) * H_ + h) * (D_ * D_);
#pragma unroll
  for (int et = 0; et < 4; ++et)
#pragma unroll
    for (int r = 0; r < 4; ++r) {
      int d = wave * 16 + lq * 4 + r;
      int e = et * 16 + ln15;
      o[d * D_ + e] = acc[et][r];
    }
}

// ---------------------------------------------------------------------------
// attn: out[e][n] = sum_d kvT[e][d] * q[n][d], *0.125, LIF over t.
// f16 MFMA exact. Writes sa f16 {0,1} at [t,b,n,c].
// grid (8 n-tiles of 128, H, B), block 256 (wave = e-tile).
// ---------------------------------------------------------------------------
__global__ __launch_bounds__(256) void attn_mfma(
    const unsigned char* __restrict__ sq2, const float* __restrict__ kv,
    unsigned short* __restrict__ sa)
{
  __shared__ _Float16 Qs[128 * 72];    // [n][d] pitch 72
  __shared__ _Float16 KVT[64 * 72];    // [e][d] pitch 72
  const int tid = threadIdx.x;
  const int lane = tid & 63, wave = tid >> 6;   // wave = e-tile
  const int ln15 = lane & 15, lq = lane >> 4;
  const int n0 = blockIdx.x * 128;
  const int h = blockIdx.y, b = blockIdx.z;

  f32x4 vm[8];
#pragma unroll
  for (int nt = 0; nt < 8; ++nt) vm[nt] = (f32x4){0.f, 0.f, 0.f, 0.f};

  for (int t = 0; t < T_; ++t) {
    __syncthreads();
    const float* kvb = kv + ((size_t)(t * B_ + b) * H_ + h) * (D_ * D_);
#pragma unroll
    for (int l = 0; l < 16; ++l) {
      int idx = l * 256 + tid;
      int e = idx & 63, d = idx >> 6;
      KVT[e * 72 + d] = (_Float16)kvb[d * 64 + e];   // ints <=1024: exact
    }
    const unsigned char* qb = sq2 + ((size_t)(t * B_ + b) * N_ + n0) * C_ + h * D_;
#pragma unroll
    for (int l = 0; l < 8; ++l) {
      int idx = l * 256 + tid;
      int n = idx >> 4, d4 = (idx & 15) * 4;
      uchar4 qu = *(const uchar4*)&qb[(size_t)n * C_ + d4];
      half4v hv;
      hv.x = qu.x ? (_Float16)1.0f : (_Float16)0.0f;
      hv.y = qu.y ? (_Float16)1.0f : (_Float16)0.0f;
      hv.z = qu.z ? (_Float16)1.0f : (_Float16)0.0f;
      hv.w = qu.w ? (_Float16)1.0f : (_Float16)0.0f;
      *(half4v*)&Qs[n * 72 + d4] = hv;
    }
    __syncthreads();

    half8v af[2];
#pragma unroll
    for (int kk = 0; kk < 2; ++kk)
      af[kk] = *(const half8v*)&KVT[(wave * 16 + ln15) * 72 + kk * 32 + lq * 8];

#pragma unroll
    for (int nt = 0; nt < 8; ++nt) {
      f32x4 a = (f32x4){0.f, 0.f, 0.f, 0.f};
#pragma unroll
      for (int kk = 0; kk < 2; ++kk) {
        half8v bf = *(const half8v*)&Qs[(nt * 16 + ln15) * 72 + kk * 32 + lq * 8];
        a = __builtin_amdgcn_mfma_f32_16x16x32_f16(af[kk], bf, a, 0, 0, 0);
      }
      unsigned short sj[4];
#pragma unroll
      for (int r = 0; r < 4; ++r) {
        float y = a[r] * 0.125f;
        float v = vm[nt][r] + (y - vm[nt][r]) * 0.5f;
        bool s = (v >= 1.0f);
        sj[r] = s ? 0x3C00 : 0;     // f16 one
        vm[nt][r] = s ? 0.f : v;
      }
      int n = n0 + nt * 16 + ln15;
      int c0 = h * D_ + wave * 16 + lq * 4;
      *(ushort4*)&sa[((size_t)(t * B_ + b) * N_ + n) * C_ + c0] =
          make_ushort4(sj[0], sj[1], sj[2], sj[3]);
    }
  }
}

// ---------------------------------------------------------------------------
// proj GEMM (2-product f16: W digits x exact f16 spikes) + connecting LIF.
// pv = acc * 2^-12 + bp. grid (4=ot, 32=ntb, 16=b), block 256.
// ---------------------------------------------------------------------------
__global__ __launch_bounds__(256) void proj_mfma(
    const _Float16* __restrict__ wb, const _Float16* __restrict__ sa,
    const float* __restrict__ bp, const float* __restrict__ x,
    float* __restrict__ out)
{
  // LDS: WS[2][128][32] f16 (16KB) + SS[4][32][32] f16 (8KB)
  __shared__ __align__(16) char lds[24576];
  const int tid = threadIdx.x;
  const int lane = tid & 63, wave = tid >> 6;
  const int ln15 = lane & 15, lq = lane >> 4;
  const int ot = blockIdx.x, ntb = blockIdx.y, b = blockIdx.z;
  const int o0 = ot * 128, n0 = ntb * 32;

  const _Float16* gsrc[6];
#pragma unroll
  for (int i = 0; i < 6; ++i) {
    int u = i * 256 + tid;
    if (u < 1024) {               // W region: 2 digits
      int s = u >> 9, rem = u & 511;
      int row = rem >> 2, pc = rem & 3;
      int lc = pc ^ ((row >> 1) & 3);
      gsrc[i] = wb + (((size_t)(3 * 2 + s)) << 18) + (size_t)(o0 + row) * C_ + lc * 8;
    } else {                      // spike region: 4t x 32 rows x 4 chunks
      int v = u - 1024;
      int t = v >> 7, rem2 = v & 127;
      int row = rem2 >> 2, pc = rem2 & 3;
      int lc = pc ^ ((row >> 1) & 3);
      gsrc[i] = sa + ((size_t)((t * B_ + b) * N_ + n0 + row)) * C_ + lc * 8;
    }
  }

  f32x4 acc[T_][2][2];
#pragma unroll
  for (int t = 0; t < T_; ++t)
#pragma unroll
    for (int mt = 0; mt < 2; ++mt)
#pragma unroll
      for (int nt = 0; nt < 2; ++nt)
        acc[t][mt][nt] = (f32x4){0.f, 0.f, 0.f, 0.f};

  int offA[2][2], offB[2];
#pragma unroll
  for (int s = 0; s < 2; ++s)
#pragma unroll
    for (int mt = 0; mt < 2; ++mt) {
      int r = wave * 32 + mt * 16 + ln15;
      offA[s][mt] = s * 8192 + r * 64 + ((lq ^ ((r >> 1) & 3)) << 4);
    }
#pragma unroll
  for (int nt = 0; nt < 2; ++nt) {
    int n = nt * 16 + ln15;
    offB[nt] = 16384 + n * 64 + ((lq ^ ((n >> 1) & 3)) << 4);
  }

  for (int kk = 0; kk < 16; ++kk) {
#pragma unroll
    for (int i = 0; i < 6; ++i)
      GLD16(gsrc[i], i * 4096 + (tid & 192) * 16);
    __syncthreads();

    half8v wa[2][2];
#pragma unroll
    for (int s = 0; s < 2; ++s)
#pragma unroll
      for (int mt = 0; mt < 2; ++mt)
        wa[s][mt] = *(const half8v*)&lds[offA[s][mt]];

#pragma unroll
    for (int t = 0; t < T_; ++t) {
      half8v xb[2];
#pragma unroll
      for (int nt = 0; nt < 2; ++nt)
        xb[nt] = *(const half8v*)&lds[offB[nt] + t * 2048];
#pragma unroll
      for (int mt = 0; mt < 2; ++mt)
#pragma unroll
        for (int nt = 0; nt < 2; ++nt) {
          f32x4 a = acc[t][mt][nt];
          a = __builtin_amdgcn_mfma_f32_16x16x32_f16(wa[1][mt], xb[nt], a, 0, 0, 0);
          a = __builtin_amdgcn_mfma_f32_16x16x32_f16(wa[0][mt], xb[nt], a, 0, 0, 0);
          acc[t][mt][nt] = a;
        }
    }
    __syncthreads();
#pragma unroll
    for (int i = 0; i < 6; ++i) gsrc[i] += 32;
  }

  // epilogue: connecting LIF with identity shortcut
#pragma unroll
  for (int mt = 0; mt < 2; ++mt)
#pragma unroll
    for (int r = 0; r < 4; ++r) {
      int o = o0 + wave * 32 + mt * 16 + lq * 4 + r;
      float bo = bp[o];
#pragma unroll
      for (int nt = 0; nt < 2; ++nt) {
        int n = n0 + nt * 16 + ln15;
        float vmem = 0.f;
#pragma unroll
        for (int t = 0; t < T_; ++t) {
          size_t base = ((size_t)(t * B_ + b) * C_ + o) * N_ + n;
          float xv = x[base];
          float pv = acc[t][mt][nt][r] * PROJ_INV_SCALE + bo;
          float v = vmem + ((pv + xv) - vmem) * 0.5f;
          bool s = (v >= 1.0f);
          out[base] = s ? 1.0f : 0.0f;
          vmem = s ? 0.f : v;
        }
      }
    }
}

// ---------------------------------------------------------------------------
extern "C" void kernel_launch(void* const* d_in, const int* in_sizes, int n_in,
                              void* d_out, int out_size, void* d_ws, size_t ws_size,
                              hipStream_t stream)
{
  const float* x  = (const float*)d_in[0];
  const float* Wq = (const float*)d_in[1];
  const float* bq = (const float*)d_in[2];
  const float* Wk = (const float*)d_in[3];
  const float* bk = (const float*)d_in[4];
  const float* Wv = (const float*)d_in[5];
  const float* bv = (const float*)d_in[6];
  const float* Wp = (const float*)d_in[7];
  const float* bp = (const float*)d_in[8];
  (void)in_sizes; (void)n_in; (void)out_size; (void)ws_size;

  unsigned char* ws = (unsigned char*)d_ws;
  unsigned char* sq = ws;                       // [t,b,n,c] transposed
  unsigned char* sk = ws + SPK_ELEMS;
  unsigned char* sv = ws + 2 * SPK_ELEMS;
  float* kvbuf = (float*)(ws + KV_OFF_N);
  _Float16* wb = (_Float16*)(ws + WB_OFF_N);
  _Float16* xs = (_Float16*)(ws + XS_OFF_N);
  unsigned short* sa = (unsigned short*)xs;  // alias digit-0 (xs dead before attn)
  float* out = (float*)d_out;

  convert_w<<<4096, 256, 0, stream>>>(Wq, Wk, Wv, Wp, wb);
  convert_x<<<dim3(32, 16, 64), dim3(32, 8), 0, stream>>>(x, xs);
  qkv_mfma<<<dim3(12, 32, 16), 256, 0, stream>>>(wb, xs, bq, bk, bv, ws);
  kv_f16<<<dim3(8, 16, 4), 256, 0, stream>>>(sk, sv, kvbuf);
  attn_mfma<<<dim3(8, 8, 16), 256, 0, stream>>>(sq, kvbuf, sa);
  proj_mfma<<<dim3(4, 32, 16), 256, 0, stream>>>(wb, (const _Float16*)sa, bp, x, out);
}